// Round 1
// baseline (3805.391 us; speedup 1.0000x reference)
//
#include <hip/hip_runtime.h>
#include <math.h>

#define BSZ 16
#define NWW 17
#define NRR 116
#define WSS 10
#define EMB 128
#define LAYN 5
#define DST 16
#define SEQL 1160
#define FRQ 581
#define EDD 170
#define LAMW 0.01f
#define EPSW 1e-5f
#define NBW (BSZ*NWW)     // 272

__device__ __forceinline__ float softplus_f(float x){
    return fmaxf(x, 0.f) + log1pf(expf(-fabsf(x)));
}
__device__ __forceinline__ float sigmoid_f(float x){
    return 1.f / (1.f + expf(-x));
}

// ---- trig tables: tab[k] = cos/sin(2*pi*k/SEQL), double precision ----
__global__ void k_tables(float* tc, float* ts){
    int k = blockIdx.x*256 + threadIdx.x;
    if (k < SEQL){
        double th = (6.283185307179586476925286766559 * (double)k) / (double)SEQL;
        tc[k] = (float)cos(th);
        ts[k] = (float)sin(th);
    }
}
// DFT matrices, t-major (for forward) and f-major (for inverse)
__global__ void k_mk_tmaj(const float* tc, const float* ts, float* Ct, float* St){
    int id = blockIdx.x*256 + threadIdx.x;
    if (id >= SEQL*FRQ) return;
    int f = id % FRQ, t = id / FRQ;
    int idx = (f*t) % SEQL;
    Ct[id] = tc[idx]; St[id] = ts[idx];
}
__global__ void k_mk_fmaj(const float* tc, const float* ts, float* Cf, float* Sf){
    int id = blockIdx.x*256 + threadIdx.x;
    if (id >= SEQL*FRQ) return;
    int t = id % SEQL, f = id / SEQL;
    int idx = (f*t) % SEQL;
    Cf[id] = tc[idx]; Sf[id] = ts[idx];
}

// ---- softmax over w_c rows ----
__global__ void k_wcsm(const float* w_c, float* wcs){
    int w = blockIdx.x; int j = threadIdx.x;
    __shared__ float red[EMB];
    float v = w_c[w*EMB + j];
    red[j] = v; __syncthreads();
    for (int s = 64; s > 0; s >>= 1){ if (j < s) red[j] = fmaxf(red[j], red[j+s]); __syncthreads(); }
    float m = red[0]; __syncthreads();
    float e = expf(v - m);
    red[j] = e; __syncthreads();
    for (int s = 64; s > 0; s >>= 1){ if (j < s) red[j] += red[j+s]; __syncthreads(); }
    wcs[w*EMB + j] = e / red[0];
}

// ---- ew[w,j] = sum_i emb[i] * fgc_w[w,0,ri,i,j] ----
__global__ void k_ew(const float* emb, const float* fgc_w, float* ewr, float* ewi){
    int id = blockIdx.x*256 + threadIdx.x;
    if (id >= NWW*EMB) return;
    int w = id / EMB, j = id % EMB;
    const float* wr = fgc_w + ((size_t)(w*LAYN + 0)*2 + 0)*EMB*EMB;
    const float* wi = wr + (size_t)EMB*EMB;
    float ar = 0.f, ai = 0.f;
    for (int i = 0; i < EMB; i++){
        float e = emb[i];
        ar += e * wr[i*EMB + j];
        ai += e * wi[i*EMB + j];
    }
    ewr[id] = ar; ewi[id] = ai;
}

// ---- forward DFT of win_seq rows: wsf[bw,f] ----
__global__ void k_dft(const float* ws, const float* Ct, const float* St,
                      float* wre, float* wim){
    int id = blockIdx.x*256 + threadIdx.x;
    if (id >= NBW*FRQ) return;
    int bw = id / FRQ, f = id % FRQ;
    const float* x = ws + (size_t)bw*SEQL;
    float sr = 0.f, si = 0.f;
    #pragma unroll 4
    for (int t = 0; t < SEQL; t++){
        float v = x[t];
        sr += v * Ct[(size_t)t*FRQ + f];
        si += v * St[(size_t)t*FRQ + f];
    }
    const float sc = 0.02936128f; // 1/sqrt(1160)
    wre[id] = sr * sc;
    wim[id] = -si * sc;
}

// ---- FGC layer 0 (rank-1 -> elementwise) ----
__global__ void k_layer1(const float* wre, const float* wim, const float* ewr, const float* ewi,
                         const float* fgc_b, float* Xre, float* Xim){
    int id = blockIdx.x*256 + threadIdx.x;
    if (id >= NBW*FRQ*EMB) return;
    int j = id & 127;
    int row = id >> 7;              // bw*FRQ + f
    int bw = row / FRQ; int w = bw % NWW;
    float re = wre[row], im = wim[row];
    const float* bb = fgc_b + ((size_t)(w*LAYN + 0)*2 + 0)*EMB;
    float br = bb[j], bi = bb[EMB + j];
    float er = ewr[w*EMB + j], ei = ewi[w*EMB + j];
    float zr = re*er - im*ei + br;
    float zi = im*er + re*ei + bi;
    Xre[id] = fmaxf(zr - LAMW, 0.f);   // softshrink(relu(z)) = max(z - lam, 0)
    Xim[id] = fmaxf(zi - LAMW, 0.f);
}

// ---- FGC layers 1..4: in-place complex GEMM per (b,w), tile 32 rows x 128 cols ----
__launch_bounds__(256, 2)
__global__ void k_fgc(float* Xre, float* Xim, const float* fgc_w, const float* fgc_b, int l){
    __shared__ float aR[EMB][33];
    __shared__ float aI[EMB][33];
    __shared__ float wR[32][EMB];
    __shared__ float wI[32][EMB];
    int bw = blockIdx.y; int w = bw % NWW;
    int f0 = blockIdx.x * 32;
    int tid = threadIdx.x;
    size_t base = (size_t)bw*FRQ*EMB;
    const float* wr = fgc_w + ((size_t)(w*LAYN + l)*2 + 0)*EMB*EMB;
    const float* wi = wr + (size_t)EMB*EMB;
    // stage A tile (transposed) — conflict-free writes (stride 33)
    for (int i = tid; i < 32*EMB; i += 256){
        int r = i >> 7, k = i & 127;
        int fr = f0 + r;
        float vr = 0.f, vi = 0.f;
        if (fr < FRQ){
            vr = Xre[base + (size_t)fr*EMB + k];
            vi = Xim[base + (size_t)fr*EMB + k];
        }
        aR[k][r] = vr; aI[k][r] = vi;
    }
    int r0 = (tid >> 5) << 2;   // 0..28
    int c0 = (tid & 31) << 2;   // 0..124
    float accR[4][4] = {}; float accI[4][4] = {};
    for (int kc = 0; kc < 4; kc++){
        __syncthreads();
        for (int i = tid; i < 32*EMB; i += 256){
            int kk = i >> 7, c = i & 127;
            wR[kk][c] = wr[(size_t)(kc*32 + kk)*EMB + c];
            wI[kk][c] = wi[(size_t)(kc*32 + kk)*EMB + c];
        }
        __syncthreads();
        for (int kk = 0; kk < 32; kk++){
            int k = kc*32 + kk;
            float ar[4], ai[4], w4[4], u4[4];
            #pragma unroll
            for (int r = 0; r < 4; r++){ ar[r] = aR[k][r0+r]; ai[r] = aI[k][r0+r]; }
            #pragma unroll
            for (int c = 0; c < 4; c++){ w4[c] = wR[kk][c0+c]; u4[c] = wI[kk][c0+c]; }
            #pragma unroll
            for (int r = 0; r < 4; r++)
                #pragma unroll
                for (int c = 0; c < 4; c++){
                    accR[r][c] += ar[r]*w4[c] - ai[r]*u4[c];
                    accI[r][c] += ai[r]*w4[c] + ar[r]*u4[c];
                }
        }
    }
    const float* bbr = fgc_b + ((size_t)(w*LAYN + l)*2 + 0)*EMB;
    const float* bbi = bbr + EMB;
    #pragma unroll
    for (int r = 0; r < 4; r++){
        int fr = f0 + r0 + r;
        if (fr >= FRQ) break;
        #pragma unroll
        for (int c = 0; c < 4; c++){
            int cc = c0 + c;
            float zr = accR[r][c] + bbr[cc];
            float zi = accI[r][c] + bbi[cc];
            Xre[base + (size_t)fr*EMB + cc] = fmaxf(zr - LAMW, 0.f);
            Xim[base + (size_t)fr*EMB + cc] = fmaxf(zi - LAMW, 0.f);
        }
    }
}

// ---- contract Xre/Xim with softmaxed w_c over E: z[bw,f] ----
__global__ void k_zred(const float* Xre, const float* Xim, const float* wcs,
                       float* zre, float* zim){
    int tid = threadIdx.x; int lane = tid & 63; int wv = tid >> 6;
    int row = blockIdx.x*4 + wv;
    if (row >= NBW*FRQ) return;
    int bw = row / FRQ; int w = bw % NWW;
    size_t b = (size_t)row*EMB;
    float c0 = wcs[w*EMB + lane], c1 = wcs[w*EMB + lane + 64];
    float sr = Xre[b + lane]*c0 + Xre[b + lane + 64]*c1;
    float si = Xim[b + lane]*c0 + Xim[b + lane + 64]*c1;
    for (int o = 32; o > 0; o >>= 1){ sr += __shfl_down(sr, o, 64); si += __shfl_down(si, o, 64); }
    if (lane == 0){ zre[row] = sr; zim[row] = si; }
}

// ---- inverse DFT: ff[bw,t] ----
__global__ void k_irfft(const float* zre, const float* zim, const float* Cf, const float* Sf,
                        float* ff){
    int id = blockIdx.x*256 + threadIdx.x;
    if (id >= NBW*SEQL) return;
    int bw = id / SEQL, t = id % SEQL;
    const float* zr = zre + (size_t)bw*FRQ;
    const float* zi = zim + (size_t)bw*FRQ;
    float acc = zr[0];
    #pragma unroll 4
    for (int f = 1; f < FRQ-1; f++){
        acc += 2.f * (zr[f]*Cf[(size_t)f*SEQL + t] - zi[f]*Sf[(size_t)f*SEQL + t]);
    }
    float ny = (t & 1) ? -zr[FRQ-1] : zr[FRQ-1];
    acc += ny;
    ff[id] = acc * 0.02936128f; // 1/sqrt(1160)
}

// ---- x1 = mean over NW of win_pcc ----
__global__ void k_x1mean(const float* pcc, float* x1){
    int id = blockIdx.x*256 + threadIdx.x;
    if (id >= BSZ*NRR*NRR) return;
    const float* p = pcc + (size_t)id*NWW;
    float s = 0.f;
    for (int w = 0; w < NWW; w++) s += p[w];
    x1[id] = s * (1.f/NWW);
}

__global__ void k_dt1(const float* x1, const float* Wdt1, float* dt1){
    int id = blockIdx.x*256 + threadIdx.x;
    if (id >= BSZ*NRR*NRR) return;
    int c = id % NRR; int bt = id / NRR;
    const float* xr = x1 + (size_t)bt*NRR;
    float s = 0.f;
    for (int m = 0; m < NRR; m++) s += xr[m] * Wdt1[m*NRR + c];
    dt1[id] = softplus_f(s);
}
__global__ void k_btct1(const float* x1, const float* WB1, const float* WC1,
                        float* BT1, float* CT1){
    int id = blockIdx.x*256 + threadIdx.x;
    if (id >= BSZ*NRR*DST) return;
    int s_ = id % DST; int bt = id / DST;
    const float* xr = x1 + (size_t)bt*NRR;
    float sb = 0.f, sc = 0.f;
    for (int m = 0; m < NRR; m++){ float v = xr[m]; sb += v*WB1[m*DST + s_]; sc += v*WC1[m*DST + s_]; }
    BT1[id] = sb; CT1[id] = sc;
}
__global__ void k_sscan1(const float* x1, const float* dt1, const float* BT1, const float* CT1,
                         const float* A1, const float* D1, float* pooled){
    int id = blockIdx.x*256 + threadIdx.x;
    if (id >= BSZ*NRR) return;
    int c = id % NRR, b = id / NRR;
    float a[DST], h[DST];
    #pragma unroll
    for (int s = 0; s < DST; s++){ a[s] = A1[c*DST + s]; h[s] = 0.f; }
    float dv = D1[c];
    float pacc = 0.f;
    for (int t = 0; t < NRR; t++){
        int o = (b*NRR + t)*NRR + c;
        float dtv = dt1[o], xv = x1[o];
        float dx = dtv * xv;
        const float* bt = BT1 + (size_t)(b*NRR + t)*DST;
        const float* ct = CT1 + (size_t)(b*NRR + t)*DST;
        float y = dv * xv;
        #pragma unroll
        for (int s = 0; s < DST; s++){
            h[s] = expf(dtv*a[s])*h[s] + dx*bt[s];
            y += h[s]*ct[s];
        }
        pacc += y;
    }
    pooled[id] = pacc * (1.f/NRR);
}
__global__ void k_out1(const float* pooled, const float* Wout1, float* out1){
    int id = blockIdx.x*256 + threadIdx.x;
    if (id >= NBW*SEQL) return;
    int k = id % SEQL; int bw = id / SEQL; int w = bw % NWW; int b = bw / NWW;
    float s = 0.f;
    for (int d = 0; d < NRR; d++) s += pooled[b*NRR + d] * Wout1[((size_t)w*NRR + d)*SEQL + k];
    out1[id] = s;
}

// ---- layernorm over SEQ per (b,w) row ----
__global__ void k_ln(const float* in, const float* g, const float* bta, float* out){
    __shared__ float row[SEQL];
    __shared__ float red[256];
    int r = blockIdx.x; int tid = threadIdx.x;
    const float* x = in + (size_t)r*SEQL;
    float s = 0.f;
    for (int i = tid; i < SEQL; i += 256){ float v = x[i]; row[i] = v; s += v; }
    red[tid] = s; __syncthreads();
    for (int st = 128; st > 0; st >>= 1){ if (tid < st) red[tid] += red[tid+st]; __syncthreads(); }
    float m = red[0] * (1.f/SEQL); __syncthreads();
    float vs = 0.f;
    for (int i = tid; i < SEQL; i += 256){ float d = row[i] - m; vs += d*d; }
    red[tid] = vs; __syncthreads();
    for (int st = 128; st > 0; st >>= 1){ if (tid < st) red[tid] += red[tid+st]; __syncthreads(); }
    float inv = 1.f / sqrtf(red[0]*(1.f/SEQL) + EPSW);
    for (int i = tid; i < SEQL; i += 256)
        out[(size_t)r*SEQL + i] = (row[i] - m)*inv*g[i] + bta[i];
}

__global__ void k_x2(const float* ga, const float* ff, float* x2){
    int id = blockIdx.x*256 + threadIdx.x;
    if (id >= NBW*SEQL) return;
    int within = id % SEQL; int q = within % WSS; int n = within / WSS;
    int bw = id / SEQL; int w = bw % NWW; int b = bw / NWW;
    const float* gr = ga + ((size_t)b*NRR + n)*NRR;
    const float* fr = ff + (size_t)(b*NWW + w)*SEQL + q;
    float s = 0.f;
    for (int m = 0; m < NRR; m++) s += gr[m] * fr[m*WSS];
    x2[id] = s;
}
__global__ void k_dt2(const float* x2, const float* Wdt2, float* dt2){
    int id = blockIdx.x*256 + threadIdx.x;
    if (id >= NBW*SEQL) return;
    int c = id % SEQL; int bt = id / SEQL;
    const float* xr = x2 + (size_t)bt*SEQL;
    float s = 0.f;
    #pragma unroll 4
    for (int m = 0; m < SEQL; m++) s += xr[m] * Wdt2[(size_t)m*SEQL + c];
    dt2[id] = softplus_f(s);
}
__global__ void k_btct2(const float* x2, const float* WB2, const float* WC2,
                        float* BT2, float* CT2){
    int id = blockIdx.x*256 + threadIdx.x;
    if (id >= NBW*DST) return;
    int s_ = id % DST; int bt = id / DST;
    const float* xr = x2 + (size_t)bt*SEQL;
    float sb = 0.f, sc = 0.f;
    for (int m = 0; m < SEQL; m++){ float v = xr[m]; sb += v*WB2[m*DST + s_]; sc += v*WC2[m*DST + s_]; }
    BT2[id] = sb; CT2[id] = sc;
}
__global__ void k_sscan2(const float* x2, const float* dt2, const float* BT2, const float* CT2,
                         const float* A2, const float* D2, float* y2){
    int id = blockIdx.x*256 + threadIdx.x;
    if (id >= BSZ*SEQL) return;
    int c = id % SEQL, b = id / SEQL;
    float a[DST], h[DST];
    #pragma unroll
    for (int s = 0; s < DST; s++){ a[s] = A2[c*DST + s]; h[s] = 0.f; }
    float dv = D2[c];
    for (int t = 0; t < NWW; t++){
        int o = (b*NWW + t)*SEQL + c;
        float dtv = dt2[o], xv = x2[o];
        float dx = dtv * xv;
        const float* bt = BT2 + (size_t)(b*NWW + t)*DST;
        const float* ct = CT2 + (size_t)(b*NWW + t)*DST;
        float y = dv * xv;
        #pragma unroll
        for (int s = 0; s < DST; s++){
            h[s] = expf(dtv*a[s])*h[s] + dx*bt[s];
            y += h[s]*ct[s];
        }
        y2[o] = y;
    }
}
__global__ void k_out2(const float* y2, const float* Wout2, float* out2){
    int id = blockIdx.x*256 + threadIdx.x;
    if (id >= NBW*SEQL) return;
    int k = id % SEQL; int bw = id / SEQL;
    const float* yr = y2 + (size_t)bw*SEQL;
    float s = 0.f;
    #pragma unroll 4
    for (int m = 0; m < SEQL; m++) s += yr[m] * Wout2[(size_t)m*SEQL + k];
    out2[id] = s;
}

// ---- gate + fusion ----
__global__ void k_gatefusion(const float* fr2, const float* tf, const float* W_gate,
                             const float* b_gate, float* fusion){
    int id = blockIdx.x*256 + threadIdx.x;
    if (id >= BSZ*NRR*EDD) return;
    int j = id % EDD; int n = (id / EDD) % NRR; int b = id / (EDD*NRR);
    float acc = b_gate[j];
    for (int w = 0; w < NWW; w++){
        const float* f2 = fr2 + (size_t)(b*NWW + w)*SEQL + n*WSS;
        const float* tp = tf  + (size_t)(b*NWW + w)*SEQL + n*WSS;
        const float* wg = W_gate + (size_t)(w*2*WSS)*EDD + j;
        #pragma unroll
        for (int q = 0; q < WSS; q++) acc += f2[q]*wg[q*EDD];
        #pragma unroll
        for (int q = 0; q < WSS; q++) acc += tp[q]*wg[(WSS+q)*EDD];
    }
    float gt = sigmoid_f(acc);
    int w_ = j / WSS, q_ = j % WSS;
    float fp = fr2[(size_t)(b*NWW + w_)*SEQL + n*WSS + q_];
    float tp = tf [(size_t)(b*NWW + w_)*SEQL + n*WSS + q_];
    fusion[id] = gt*fp + (1.f - gt)*tp;
}

// ---- router: LN(170) -> 4 logits -> top2 softmax gates ----
__global__ void k_gates(const float* fusion, const float* rg, const float* rb,
                        const float* Wr, const float* brr, float* gatesE){
    int bn = blockIdx.x; int lane = threadIdx.x;
    const float* x = fusion + (size_t)bn*EDD;
    bool v2ok = (lane + 128) < EDD;
    float v0 = x[lane];
    float v1 = x[lane + 64];
    float v2 = v2ok ? x[lane + 128] : 0.f;
    float s = v0 + v1 + v2;
    for (int o = 32; o > 0; o >>= 1) s += __shfl_xor(s, o, 64);
    float m = s * (1.f/EDD);
    float d0 = v0 - m, d1 = v1 - m, d2 = v2ok ? (v2 - m) : 0.f;
    float vs = d0*d0 + d1*d1 + d2*d2;
    for (int o = 32; o > 0; o >>= 1) vs += __shfl_xor(vs, o, 64);
    float inv = 1.f / sqrtf(vs*(1.f/EDD) + EPSW);
    float r0 = d0*inv*rg[lane] + rb[lane];
    float r1 = d1*inv*rg[lane+64] + rb[lane+64];
    float r2 = v2ok ? (d2*inv*rg[lane+128] + rb[lane+128]) : 0.f;
    float pl[4];
    #pragma unroll
    for (int e = 0; e < 4; e++){
        float p = r0*Wr[lane*4 + e] + r1*Wr[(lane+64)*4 + e];
        if (v2ok) p += r2*Wr[(lane+128)*4 + e];
        for (int o = 32; o > 0; o >>= 1) p += __shfl_xor(p, o, 64);
        pl[e] = p;
    }
    if (lane == 0){
        float lg[4];
        #pragma unroll
        for (int e = 0; e < 4; e++) lg[e] = pl[e] + brr[e];
        int i0 = 0;
        for (int e = 1; e < 4; e++) if (lg[e] > lg[i0]) i0 = e;
        int i1 = -1;
        for (int e = 0; e < 4; e++) if (e != i0 && (i1 < 0 || lg[e] > lg[i1])) i1 = e;
        float e1 = expf(lg[i1] - lg[i0]);
        float w0 = 1.f/(1.f + e1), w1 = e1/(1.f + e1);
        float g[4] = {0.f,0.f,0.f,0.f};
        g[i0] = w0; g[i1] = w1;
        #pragma unroll
        for (int e = 0; e < 4; e++) gatesE[bn*4 + e] = g[e];
    }
}

__global__ void k_support(const float* fusion, const float* We, float* support){
    int id = blockIdx.x*256 + threadIdx.x;
    if (id >= BSZ*4*NRR*EDD) return;
    int g = id % EDD; int n = (id / EDD) % NRR; int e = (id / (EDD*NRR)) % 4; int b = id / (EDD*NRR*4);
    const float* fu = fusion + ((size_t)b*NRR + n)*EDD;
    const float* w = We + (size_t)e*EDD*EDD + g;
    float s = 0.f;
    for (int f = 0; f < EDD; f++) s += fu[f] * w[(size_t)f*EDD];
    support[id] = s;
}
__global__ void k_eout(const float* ga, const float* support, float* eout){
    int id = blockIdx.x*256 + threadIdx.x;
    if (id >= BSZ*4*NRR*EDD) return;
    int g = id % EDD; int n = (id / EDD) % NRR; int e = (id / (EDD*NRR)) % 4; int b = id / (EDD*NRR*4);
    const float* gr = ga + ((size_t)b*NRR + n)*NRR;
    const float* sp = support + ((size_t)(b*4 + e)*NRR)*EDD + g;
    float s = 0.f;
    for (int m = 0; m < NRR; m++) s += gr[m] * sp[(size_t)m*EDD];
    eout[id] = fmaxf(s, 0.f);
}
__global__ void k_moe(const float* eout, const float* gatesE, float* moe){
    int id = blockIdx.x*256 + threadIdx.x;
    if (id >= BSZ*NRR*EDD) return;
    int g = id % EDD; int n = (id / EDD) % NRR; int b = id / (EDD*NRR);
    const float* gt = gatesE + ((size_t)b*NRR + n)*4;
    float s = 0.f;
    #pragma unroll
    for (int e = 0; e < 4; e++)
        s += eout[((size_t)(b*4 + e)*NRR + n)*EDD + g] * gt[e];
    moe[id] = s;
}

#define MLPK (NRR*EDD)   // 19720
#define KSPLIT 16
#define KCH 1233
__global__ void k_mlp1p(const float* moe, const float* W1, float* part1){
    int id = blockIdx.x*256 + threadIdx.x;
    if (id >= KSPLIT*BSZ*512) return;
    int j = id % 512; int b = (id / 512) % BSZ; int kc = id / (512*BSZ);
    int i0 = kc*KCH; int i1 = i0 + KCH; if (i1 > MLPK) i1 = MLPK;
    const float* mo = moe + (size_t)b*MLPK;
    float s = 0.f;
    for (int i = i0; i < i1; i++) s += mo[i] * W1[(size_t)i*512 + j];
    part1[id] = s;
}
__global__ void k_mlp1c(const float* part1, const float* b1, float* h1){
    int id = blockIdx.x*256 + threadIdx.x;
    if (id >= BSZ*512) return;
    float s = 0.f;
    #pragma unroll
    for (int kc = 0; kc < KSPLIT; kc++) s += part1[(size_t)kc*BSZ*512 + id];
    const float sc = 0.99999500003750f; // 1/sqrt(1+1e-5)
    h1[id] = fmaxf((s + b1[id % 512]) * sc, 0.f);
}
__global__ void k_mlp2(const float* h1, const float* W2, const float* b2, float* h2){
    int id = blockIdx.x*256 + threadIdx.x;
    if (id >= BSZ*256) return;
    int j = id % 256; int b = id / 256;
    const float* h = h1 + (size_t)b*512;
    float s = 0.f;
    for (int i = 0; i < 512; i++) s += h[i] * W2[(size_t)i*256 + j];
    const float sc = 0.99999500003750f;
    h2[id] = fmaxf((s + b2[j]) * sc, 0.f);
}
__global__ void k_mlp3(const float* h2, const float* W3, const float* b3, float* h3){
    int id = blockIdx.x*256 + threadIdx.x;
    if (id >= BSZ*128) return;
    int j = id % 128; int b = id / 128;
    const float* h = h2 + (size_t)b*256;
    float s = 0.f;
    for (int i = 0; i < 256; i++) s += h[i] * W3[(size_t)i*128 + j];
    const float sc = 0.99999500003750f;
    h3[id] = fmaxf((s + b3[j]) * sc, 0.f);
}
__global__ void k_mlp4(const float* h3, const float* W4, const float* b4, float* out){
    int id = threadIdx.x;
    if (id >= BSZ*2) return;
    int o = id % 2; int b = id / 2;
    const float* h = h3 + (size_t)b*128;
    float s = 0.f;
    for (int i = 0; i < 128; i++) s += h[i] * W4[i*2 + o];
    out[id] = s + b4[o];
}

extern "C" void kernel_launch(void* const* d_in, const int* in_sizes, int n_in,
                              void* d_out, int out_size, void* d_ws, size_t ws_size,
                              hipStream_t stream){
    (void)in_sizes; (void)n_in; (void)out_size;
    const float* win_seq = (const float*)d_in[0];
    const float* win_pcc = (const float*)d_in[1];
    const float* ga      = (const float*)d_in[2];
    const float* emb     = (const float*)d_in[4];
    const float* fgc_w   = (const float*)d_in[5];
    const float* fgc_b   = (const float*)d_in[6];
    const float* w_c     = (const float*)d_in[7];
    const float* ln_g    = (const float*)d_in[8];
    const float* ln_b    = (const float*)d_in[9];
    const float* A1      = (const float*)d_in[10];
    const float* WB1     = (const float*)d_in[11];
    const float* WC1     = (const float*)d_in[12];
    const float* Wdt1    = (const float*)d_in[13];
    const float* D1      = (const float*)d_in[14];
    const float* Wout1   = (const float*)d_in[15];
    const float* A2      = (const float*)d_in[16];
    const float* WB2     = (const float*)d_in[17];
    const float* WC2     = (const float*)d_in[18];
    const float* Wdt2    = (const float*)d_in[19];
    const float* D2      = (const float*)d_in[20];
    const float* Wout2   = (const float*)d_in[21];
    const float* W_gate  = (const float*)d_in[22];
    const float* b_gate  = (const float*)d_in[23];
    const float* rln_g   = (const float*)d_in[24];
    const float* rln_b   = (const float*)d_in[25];
    const float* Wr      = (const float*)d_in[26];
    const float* brr     = (const float*)d_in[27];
    const float* We      = (const float*)d_in[28];
    const float* W1      = (const float*)d_in[29];
    const float* b1      = (const float*)d_in[30];
    const float* W2      = (const float*)d_in[31];
    const float* b2      = (const float*)d_in[32];
    const float* W3      = (const float*)d_in[33];
    const float* b3      = (const float*)d_in[34];
    const float* W4      = (const float*)d_in[35];
    const float* b4      = (const float*)d_in[36];
    float* out = (float*)d_out;
    float* ws  = (float*)d_ws;

    size_t off = 0;
    auto alloc = [&](size_t n){ size_t o = off; off += (n + 63) & ~(size_t)63; return o; };
    size_t o_tabc = alloc(SEQL), o_tabs = alloc(SEQL);
    size_t o_Ct = alloc((size_t)SEQL*FRQ), o_St = alloc((size_t)SEQL*FRQ);
    size_t o_Cf = alloc((size_t)SEQL*FRQ), o_Sf = alloc((size_t)SEQL*FRQ);
    size_t o_wcs = alloc(NWW*EMB);
    size_t o_ewr = alloc(NWW*EMB), o_ewi = alloc(NWW*EMB);
    size_t o_wre = alloc((size_t)NBW*FRQ), o_wim = alloc((size_t)NBW*FRQ);
    size_t o_Xre = alloc((size_t)NBW*FRQ*EMB), o_Xim = alloc((size_t)NBW*FRQ*EMB);
    size_t o_zre = alloc((size_t)NBW*FRQ), o_zim = alloc((size_t)NBW*FRQ);
    size_t o_ff  = alloc((size_t)NBW*SEQL);
    size_t o_x1  = alloc((size_t)BSZ*NRR*NRR);
    size_t o_dt1 = alloc((size_t)BSZ*NRR*NRR);
    size_t o_BT1 = alloc((size_t)BSZ*NRR*DST), o_CT1 = alloc((size_t)BSZ*NRR*DST);
    size_t o_pool= alloc((size_t)BSZ*NRR);
    size_t o_o1  = alloc((size_t)NBW*SEQL);
    size_t o_tf  = alloc((size_t)NBW*SEQL);
    size_t o_x2  = alloc((size_t)NBW*SEQL);
    size_t o_dt2 = alloc((size_t)NBW*SEQL);
    size_t o_BT2 = alloc((size_t)NBW*DST), o_CT2 = alloc((size_t)NBW*DST);
    size_t o_y2  = alloc((size_t)NBW*SEQL);
    size_t o_o2  = alloc((size_t)NBW*SEQL);
    size_t o_fr2 = alloc((size_t)NBW*SEQL);
    size_t o_fus = alloc((size_t)BSZ*NRR*EDD);
    size_t o_gte = alloc((size_t)BSZ*NRR*4);
    size_t o_sup = alloc((size_t)BSZ*4*NRR*EDD);
    size_t o_eo  = alloc((size_t)BSZ*4*NRR*EDD);
    size_t o_moe = alloc((size_t)BSZ*NRR*EDD);
    size_t o_p1  = alloc((size_t)KSPLIT*BSZ*512);
    size_t o_h1  = alloc((size_t)BSZ*512);
    size_t o_h2  = alloc((size_t)BSZ*256);
    size_t o_h3  = alloc((size_t)BSZ*128);
    if (ws_size < off*sizeof(float)) return; // workspace too small -> visible failure

    #define WSP(o) (ws + (o))
    int nMk = (SEQL*FRQ + 255)/256;
    k_tables<<<(SEQL+255)/256, 256, 0, stream>>>(WSP(o_tabc), WSP(o_tabs));
    k_mk_tmaj<<<nMk, 256, 0, stream>>>(WSP(o_tabc), WSP(o_tabs), WSP(o_Ct), WSP(o_St));
    k_mk_fmaj<<<nMk, 256, 0, stream>>>(WSP(o_tabc), WSP(o_tabs), WSP(o_Cf), WSP(o_Sf));
    k_wcsm<<<NWW, EMB, 0, stream>>>(w_c, WSP(o_wcs));
    k_ew<<<(NWW*EMB+255)/256, 256, 0, stream>>>(emb, fgc_w, WSP(o_ewr), WSP(o_ewi));
    k_dft<<<(NBW*FRQ+255)/256, 256, 0, stream>>>(win_seq, WSP(o_Ct), WSP(o_St), WSP(o_wre), WSP(o_wim));
    k_layer1<<<(NBW*FRQ*EMB)/256, 256, 0, stream>>>(WSP(o_wre), WSP(o_wim), WSP(o_ewr), WSP(o_ewi),
                                                    fgc_b, WSP(o_Xre), WSP(o_Xim));
    for (int l = 1; l < LAYN; l++)
        k_fgc<<<dim3(19, NBW), 256, 0, stream>>>(WSP(o_Xre), WSP(o_Xim), fgc_w, fgc_b, l);
    k_zred<<<(NBW*FRQ+3)/4, 256, 0, stream>>>(WSP(o_Xre), WSP(o_Xim), WSP(o_wcs), WSP(o_zre), WSP(o_zim));
    k_irfft<<<(NBW*SEQL+255)/256, 256, 0, stream>>>(WSP(o_zre), WSP(o_zim), WSP(o_Cf), WSP(o_Sf), WSP(o_ff));
    // branch 1: pcc -> sscan1 -> out1 -> LN
    k_x1mean<<<(BSZ*NRR*NRR+255)/256, 256, 0, stream>>>(win_pcc, WSP(o_x1));
    k_dt1<<<(BSZ*NRR*NRR+255)/256, 256, 0, stream>>>(WSP(o_x1), Wdt1, WSP(o_dt1));
    k_btct1<<<(BSZ*NRR*DST+255)/256, 256, 0, stream>>>(WSP(o_x1), WB1, WC1, WSP(o_BT1), WSP(o_CT1));
    k_sscan1<<<(BSZ*NRR+255)/256, 256, 0, stream>>>(WSP(o_x1), WSP(o_dt1), WSP(o_BT1), WSP(o_CT1),
                                                    A1, D1, WSP(o_pool));
    k_out1<<<(NBW*SEQL+255)/256, 256, 0, stream>>>(WSP(o_pool), Wout1, WSP(o_o1));
    k_ln<<<NBW, 256, 0, stream>>>(WSP(o_o1), ln_g, ln_b, WSP(o_tf));
    // branch 2: freq_feat -> adj -> sscan2 -> out2 -> LN
    k_x2<<<(NBW*SEQL+255)/256, 256, 0, stream>>>(ga, WSP(o_ff), WSP(o_x2));
    k_dt2<<<(NBW*SEQL+255)/256, 256, 0, stream>>>(WSP(o_x2), Wdt2, WSP(o_dt2));
    k_btct2<<<(NBW*DST+255)/256, 256, 0, stream>>>(WSP(o_x2), WB2, WC2, WSP(o_BT2), WSP(o_CT2));
    k_sscan2<<<(BSZ*SEQL+255)/256, 256, 0, stream>>>(WSP(o_x2), WSP(o_dt2), WSP(o_BT2), WSP(o_CT2),
                                                     A2, D2, WSP(o_y2));
    k_out2<<<(NBW*SEQL+255)/256, 256, 0, stream>>>(WSP(o_y2), Wout2, WSP(o_o2));
    k_ln<<<NBW, 256, 0, stream>>>(WSP(o_o2), ln_g, ln_b, WSP(o_fr2));
    // fusion + MoE + MLP
    k_gatefusion<<<(BSZ*NRR*EDD+255)/256, 256, 0, stream>>>(WSP(o_fr2), WSP(o_tf), W_gate, b_gate, WSP(o_fus));
    k_gates<<<BSZ*NRR, 64, 0, stream>>>(WSP(o_fus), rln_g, rln_b, Wr, brr, WSP(o_gte));
    k_support<<<(BSZ*4*NRR*EDD+255)/256, 256, 0, stream>>>(WSP(o_fus), We, WSP(o_sup));
    k_eout<<<(BSZ*4*NRR*EDD+255)/256, 256, 0, stream>>>(ga, WSP(o_sup), WSP(o_eo));
    k_moe<<<(BSZ*NRR*EDD+255)/256, 256, 0, stream>>>(WSP(o_eo), WSP(o_gte), WSP(o_moe));
    k_mlp1p<<<(KSPLIT*BSZ*512)/256, 256, 0, stream>>>(WSP(o_moe), W1, WSP(o_p1));
    k_mlp1c<<<(BSZ*512)/256, 256, 0, stream>>>(WSP(o_p1), b1, WSP(o_h1));
    k_mlp2<<<(BSZ*256)/256, 256, 0, stream>>>(WSP(o_h1), W2, b2, WSP(o_h2));
    k_mlp3<<<(BSZ*128+255)/256, 256, 0, stream>>>(WSP(o_h2), W3, b3, WSP(o_h3));
    k_mlp4<<<1, 64, 0, stream>>>(WSP(o_h3), W4, b4, out);
    #undef WSP
}

// Round 2
// 2294.585 us; speedup vs baseline: 1.6584x; 1.6584x over previous
//
#include <hip/hip_runtime.h>
#include <math.h>

#define BSZ 16
#define NWW 17
#define NRR 116
#define WSS 10
#define EMB 128
#define LAYN 5
#define DST 16
#define SEQL 1160
#define FRQ 581
#define EDD 170
#define LAMW 0.01f
#define EPSW 1e-5f
#define NBW (BSZ*NWW)     // 272

// split-precision scales for f16 MFMA emulation of fp32 GEMM
#define SXF 1024.0f              // X scale (2^10)
#define SWF 4096.0f              // W scale (2^12)
#define INVS 2.384185791015625e-07f  // 1/(SXF*SWF) = 2^-22

typedef _Float16 half8 __attribute__((ext_vector_type(8)));
typedef float float4v __attribute__((ext_vector_type(4)));

__device__ __forceinline__ float softplus_f(float x){
    return fmaxf(x, 0.f) + log1pf(expf(-fabsf(x)));
}
__device__ __forceinline__ float sigmoid_f(float x){
    return 1.f / (1.f + expf(-x));
}

// ---- trig tables: tab[k] = cos/sin(2*pi*k/SEQL), double precision ----
__global__ void k_tables(float* tc, float* ts){
    int k = blockIdx.x*256 + threadIdx.x;
    if (k < SEQL){
        double th = (6.283185307179586476925286766559 * (double)k) / (double)SEQL;
        tc[k] = (float)cos(th);
        ts[k] = (float)sin(th);
    }
}
// DFT matrices, t-major (for forward) and f-major (for inverse)
__global__ void k_mk_tmaj(const float* tc, const float* ts, float* Ct, float* St){
    int id = blockIdx.x*256 + threadIdx.x;
    if (id >= SEQL*FRQ) return;
    int f = id % FRQ, t = id / FRQ;
    int idx = (f*t) % SEQL;
    Ct[id] = tc[idx]; St[id] = ts[idx];
}
__global__ void k_mk_fmaj(const float* tc, const float* ts, float* Cf, float* Sf){
    int id = blockIdx.x*256 + threadIdx.x;
    if (id >= SEQL*FRQ) return;
    int t = id % SEQL, f = id / SEQL;
    int idx = (f*t) % SEQL;
    Cf[id] = tc[idx]; Sf[id] = ts[idx];
}

// ---- softmax over w_c rows ----
__global__ void k_wcsm(const float* w_c, float* wcs){
    int w = blockIdx.x; int j = threadIdx.x;
    __shared__ float red[EMB];
    float v = w_c[w*EMB + j];
    red[j] = v; __syncthreads();
    for (int s = 64; s > 0; s >>= 1){ if (j < s) red[j] = fmaxf(red[j], red[j+s]); __syncthreads(); }
    float m = red[0]; __syncthreads();
    float e = expf(v - m);
    red[j] = e; __syncthreads();
    for (int s = 64; s > 0; s >>= 1){ if (j < s) red[j] += red[j+s]; __syncthreads(); }
    wcs[w*EMB + j] = e / red[0];
}

// ---- ew[w,j] = sum_i emb[i] * fgc_w[w,0,ri,i,j] ----
__global__ void k_ew(const float* emb, const float* fgc_w, float* ewr, float* ewi){
    int id = blockIdx.x*256 + threadIdx.x;
    if (id >= NWW*EMB) return;
    int w = id / EMB, j = id % EMB;
    const float* wr = fgc_w + ((size_t)(w*LAYN + 0)*2 + 0)*EMB*EMB;
    const float* wi = wr + (size_t)EMB*EMB;
    float ar = 0.f, ai = 0.f;
    for (int i = 0; i < EMB; i++){
        float e = emb[i];
        ar += e * wr[i*EMB + j];
        ai += e * wi[i*EMB + j];
    }
    ewr[id] = ar; ewi[id] = ai;
}

// ---- forward DFT of win_seq rows: wsf[bw,f] ----
__global__ void k_dft(const float* ws, const float* Ct, const float* St,
                      float* wre, float* wim){
    int id = blockIdx.x*256 + threadIdx.x;
    if (id >= NBW*FRQ) return;
    int bw = id / FRQ, f = id % FRQ;
    const float* x = ws + (size_t)bw*SEQL;
    float sr = 0.f, si = 0.f;
    #pragma unroll 4
    for (int t = 0; t < SEQL; t++){
        float v = x[t];
        sr += v * Ct[(size_t)t*FRQ + f];
        si += v * St[(size_t)t*FRQ + f];
    }
    const float sc = 0.02936128f; // 1/sqrt(1160)
    wre[id] = sr * sc;
    wim[id] = -si * sc;
}

// ---- weight prep: transpose + scale + fp16 hi/lo split for layers 1..4 ----
// WT layout: [(w*4 + (l-1))*2 + ri][n=out_col][k=in_idx], fp16, scaled by SWF
__global__ void k_wprep(const float* fgc_w, _Float16* WThi, _Float16* WTlo){
    __shared__ float T[64][65];
    int b = blockIdx.x;              // 544 blocks
    int tile = b & 3; int wlr = b >> 2;     // wlr in [0,136)
    int ri = wlr & 1; int wl = wlr >> 1;    // wl = w*4 + (l-1)
    int w = wl >> 2; int lm1 = wl & 3;
    const float* src = fgc_w + ((size_t)(w*LAYN + (lm1+1))*2 + ri)*EMB*EMB;
    int i0 = (tile >> 1)*64, j0 = (tile & 1)*64;
    for (int e = threadIdx.x; e < 4096; e += 256){
        int ii = e >> 6, jj = e & 63;
        T[ii][jj] = src[(size_t)(i0+ii)*EMB + (j0+jj)];
    }
    __syncthreads();
    size_t dbase = (size_t)wlr*16384;
    for (int e = threadIdx.x; e < 4096; e += 256){
        int jj = e >> 6, ii = e & 63;   // write with k (=i) fastest
        float v = T[ii][jj] * SWF;
        _Float16 h = (_Float16)v;
        _Float16 lo = (_Float16)(v - (float)h);
        size_t o = dbase + (size_t)(j0+jj)*EMB + (i0+ii);
        WThi[o] = h; WTlo[o] = lo;
    }
}

// ---- fused FGC: layer0 (rank-1) + 4 complex GEMM layers (f16 split MFMA) + zred ----
// block: 32 rows (freq bins) of one bw; 256 threads = 4 waves, wave = 32 rows x 32 cols
__launch_bounds__(256, 3)
__global__ void k_fgc_fused(const float* wre, const float* wim,
                            const float* ewr, const float* ewi,
                            const float* fgc_b, const float* wcs,
                            const _Float16* WThi, const _Float16* WTlo,
                            float* zre, float* zim){
    __shared__ _Float16 AhR[32*136];
    __shared__ _Float16 AlR[32*136];
    __shared__ _Float16 AhI[32*136];
    __shared__ _Float16 AlI[32*136];
    __shared__ float OUTR[16*130];
    __shared__ float OUTI[16*130];
    int tid = threadIdx.x;
    int bw = blockIdx.y; int w = bw % NWW;
    int f0 = blockIdx.x * 32;
    int lane = tid & 63, wv = tid >> 6;
    int c = lane & 15, q = lane >> 4;

    // ---- layer 0: X0[f][j] = relu(wre*ewr - wim*ewi + br - lam), split to LDS ----
    {
        int f = tid >> 3;            // 0..31
        int j0 = (tid & 7) << 4;     // 0..112
        int fg = f0 + f;
        float re = 0.f, im = 0.f;
        if (fg < FRQ){ re = wre[(size_t)bw*FRQ + fg]; im = wim[(size_t)bw*FRQ + fg]; }
        const float* br = fgc_b + (size_t)(w*LAYN + 0)*2*EMB;
        const float* bi = br + EMB;
        #pragma unroll
        for (int g = 0; g < 2; g++){
            half8 hR, lR, hI, lI;
            #pragma unroll
            for (int u = 0; u < 8; u++){
                int jj = j0 + g*8 + u;
                float er = ewr[w*EMB + jj], ei = ewi[w*EMB + jj];
                float xr = fmaxf(re*er - im*ei + br[jj] - LAMW, 0.f) * SXF;
                float xi = fmaxf(im*er + re*ei + bi[jj] - LAMW, 0.f) * SXF;
                _Float16 h1 = (_Float16)xr; hR[u] = h1; lR[u] = (_Float16)(xr - (float)h1);
                _Float16 h2 = (_Float16)xi; hI[u] = h2; lI[u] = (_Float16)(xi - (float)h2);
            }
            int ao = f*136 + j0 + g*8;
            *(half8*)&AhR[ao] = hR;
            *(half8*)&AlR[ao] = lR;
            *(half8*)&AhI[ao] = hI;
            *(half8*)&AlI[ao] = lI;
        }
    }
    __syncthreads();

    for (int l = 1; l <= 4; l++){
        size_t wbase = (size_t)((w*4 + (l-1))*2)*16384;
        const _Float16* WhR = WThi + wbase;
        const _Float16* WlR = WTlo + wbase;
        const _Float16* WhI = WThi + wbase + 16384;
        const _Float16* WlI = WTlo + wbase + 16384;
        float4v Prr[2][2], Pii[2][2], Pri[2][2], Pir[2][2];
        #pragma unroll
        for (int rt = 0; rt < 2; rt++)
            #pragma unroll
            for (int ct = 0; ct < 2; ct++){
                #pragma unroll
                for (int u = 0; u < 4; u++){
                    Prr[rt][ct][u] = 0.f; Pii[rt][ct][u] = 0.f;
                    Pri[rt][ct][u] = 0.f; Pir[rt][ct][u] = 0.f;
                }
            }
        for (int kc = 0; kc < 4; kc++){
            int ko = kc*32 + q*8;
            half8 ahR[2], alR[2], ahI[2], alI[2];
            #pragma unroll
            for (int rt = 0; rt < 2; rt++){
                int ao = (rt*16 + c)*136 + ko;
                ahR[rt] = *(const half8*)&AhR[ao];
                alR[rt] = *(const half8*)&AlR[ao];
                ahI[rt] = *(const half8*)&AhI[ao];
                alI[rt] = *(const half8*)&AlI[ao];
            }
            #pragma unroll
            for (int ct = 0; ct < 2; ct++){
                size_t woff = (size_t)(wv*32 + ct*16 + c)*128 + ko;
                half8 whR = *(const half8*)&WhR[woff];
                half8 wlR = *(const half8*)&WlR[woff];
                half8 whI = *(const half8*)&WhI[woff];
                half8 wlI = *(const half8*)&WlI[woff];
                #pragma unroll
                for (int rt = 0; rt < 2; rt++){
                    // Ar*Wr
                    Prr[rt][ct] = __builtin_amdgcn_mfma_f32_16x16x32_f16(ahR[rt], whR, Prr[rt][ct], 0,0,0);
                    Prr[rt][ct] = __builtin_amdgcn_mfma_f32_16x16x32_f16(ahR[rt], wlR, Prr[rt][ct], 0,0,0);
                    Prr[rt][ct] = __builtin_amdgcn_mfma_f32_16x16x32_f16(alR[rt], whR, Prr[rt][ct], 0,0,0);
                    // Ai*Wi
                    Pii[rt][ct] = __builtin_amdgcn_mfma_f32_16x16x32_f16(ahI[rt], whI, Pii[rt][ct], 0,0,0);
                    Pii[rt][ct] = __builtin_amdgcn_mfma_f32_16x16x32_f16(ahI[rt], wlI, Pii[rt][ct], 0,0,0);
                    Pii[rt][ct] = __builtin_amdgcn_mfma_f32_16x16x32_f16(alI[rt], whI, Pii[rt][ct], 0,0,0);
                    // Ar*Wi
                    Pri[rt][ct] = __builtin_amdgcn_mfma_f32_16x16x32_f16(ahR[rt], whI, Pri[rt][ct], 0,0,0);
                    Pri[rt][ct] = __builtin_amdgcn_mfma_f32_16x16x32_f16(ahR[rt], wlI, Pri[rt][ct], 0,0,0);
                    Pri[rt][ct] = __builtin_amdgcn_mfma_f32_16x16x32_f16(alR[rt], whI, Pri[rt][ct], 0,0,0);
                    // Ai*Wr
                    Pir[rt][ct] = __builtin_amdgcn_mfma_f32_16x16x32_f16(ahI[rt], whR, Pir[rt][ct], 0,0,0);
                    Pir[rt][ct] = __builtin_amdgcn_mfma_f32_16x16x32_f16(ahI[rt], wlR, Pir[rt][ct], 0,0,0);
                    Pir[rt][ct] = __builtin_amdgcn_mfma_f32_16x16x32_f16(alI[rt], whR, Pir[rt][ct], 0,0,0);
                }
            }
        }
        __syncthreads();   // all waves done reading A planes
        const float* bR = fgc_b + (size_t)(w*LAYN + l)*2*EMB;
        const float* bI = bR + EMB;
        #pragma unroll
        for (int chunk = 0; chunk < 2; chunk++){
            // epilogue: rows chunk*16..+16, this wave's 32 cols (D: col=lane&15, row=q*4+reg)
            #pragma unroll
            for (int ct = 0; ct < 2; ct++){
                int n = wv*32 + ct*16 + c;
                float biasR = bR[n] - LAMW, biasI = bI[n] - LAMW;
                #pragma unroll
                for (int r = 0; r < 4; r++){
                    int row = q*4 + r;
                    float vR = (Prr[chunk][ct][r] - Pii[chunk][ct][r])*INVS + biasR;
                    float vI = (Pir[chunk][ct][r] + Pri[chunk][ct][r])*INVS + biasI;
                    OUTR[row*130 + n] = fmaxf(vR, 0.f);
                    OUTI[row*130 + n] = fmaxf(vI, 0.f);
                }
            }
            __syncthreads();
            if (l < 4){
                // repack chunk into A planes (split to fp16 hi/lo, scaled)
                int fch = tid >> 4;            // 0..15
                int j0r = (tid & 15) << 3;     // 0..120
                half8 hR, lR, hI, lI;
                #pragma unroll
                for (int u = 0; u < 8; u++){
                    float xr = OUTR[fch*130 + j0r + u] * SXF;
                    float xi = OUTI[fch*130 + j0r + u] * SXF;
                    _Float16 h1 = (_Float16)xr; hR[u] = h1; lR[u] = (_Float16)(xr - (float)h1);
                    _Float16 h2 = (_Float16)xi; hI[u] = h2; lI[u] = (_Float16)(xi - (float)h2);
                }
                int ao = (chunk*16 + fch)*136 + j0r;
                *(half8*)&AhR[ao] = hR;
                *(half8*)&AlR[ao] = lR;
                *(half8*)&AhI[ao] = hI;
                *(half8*)&AlI[ao] = lI;
            } else {
                // final layer: contract with softmaxed w_c over EMB -> zre/zim
                int fch = tid >> 4;
                int j0r = (tid & 15) << 3;
                float sR = 0.f, sI = 0.f;
                #pragma unroll
                for (int u = 0; u < 8; u++){
                    float cwc = wcs[w*EMB + j0r + u];
                    sR += OUTR[fch*130 + j0r + u] * cwc;
                    sI += OUTI[fch*130 + j0r + u] * cwc;
                }
                #pragma unroll
                for (int o = 8; o > 0; o >>= 1){
                    sR += __shfl_down(sR, o, 64);
                    sI += __shfl_down(sI, o, 64);
                }
                int fg = f0 + chunk*16 + fch;
                if ((tid & 15) == 0 && fg < FRQ){
                    zre[(size_t)bw*FRQ + fg] = sR;
                    zim[(size_t)bw*FRQ + fg] = sI;
                }
            }
            __syncthreads();
        }
    }
}

// ---- inverse DFT: ff[bw,t] ----
__global__ void k_irfft(const float* zre, const float* zim, const float* Cf, const float* Sf,
                        float* ff){
    int id = blockIdx.x*256 + threadIdx.x;
    if (id >= NBW*SEQL) return;
    int bw = id / SEQL, t = id % SEQL;
    const float* zr = zre + (size_t)bw*FRQ;
    const float* zi = zim + (size_t)bw*FRQ;
    float acc = zr[0];
    #pragma unroll 4
    for (int f = 1; f < FRQ-1; f++){
        acc += 2.f * (zr[f]*Cf[(size_t)f*SEQL + t] - zi[f]*Sf[(size_t)f*SEQL + t]);
    }
    float ny = (t & 1) ? -zr[FRQ-1] : zr[FRQ-1];
    acc += ny;
    ff[id] = acc * 0.02936128f; // 1/sqrt(1160)
}

// ---- x1 = mean over NW of win_pcc ----
__global__ void k_x1mean(const float* pcc, float* x1){
    int id = blockIdx.x*256 + threadIdx.x;
    if (id >= BSZ*NRR*NRR) return;
    const float* p = pcc + (size_t)id*NWW;
    float s = 0.f;
    for (int w = 0; w < NWW; w++) s += p[w];
    x1[id] = s * (1.f/NWW);
}

__global__ void k_dt1(const float* x1, const float* Wdt1, float* dt1){
    int id = blockIdx.x*256 + threadIdx.x;
    if (id >= BSZ*NRR*NRR) return;
    int c = id % NRR; int bt = id / NRR;
    const float* xr = x1 + (size_t)bt*NRR;
    float s = 0.f;
    for (int m = 0; m < NRR; m++) s += xr[m] * Wdt1[m*NRR + c];
    dt1[id] = softplus_f(s);
}
__global__ void k_btct1(const float* x1, const float* WB1, const float* WC1,
                        float* BT1, float* CT1){
    int id = blockIdx.x*256 + threadIdx.x;
    if (id >= BSZ*NRR*DST) return;
    int s_ = id % DST; int bt = id / DST;
    const float* xr = x1 + (size_t)bt*NRR;
    float sb = 0.f, sc = 0.f;
    for (int m = 0; m < NRR; m++){ float v = xr[m]; sb += v*WB1[m*DST + s_]; sc += v*WC1[m*DST + s_]; }
    BT1[id] = sb; CT1[id] = sc;
}
__global__ void k_sscan1(const float* x1, const float* dt1, const float* BT1, const float* CT1,
                         const float* A1, const float* D1, float* pooled){
    int id = blockIdx.x*256 + threadIdx.x;
    if (id >= BSZ*NRR) return;
    int c = id % NRR, b = id / NRR;
    float a[DST], h[DST];
    #pragma unroll
    for (int s = 0; s < DST; s++){ a[s] = A1[c*DST + s]; h[s] = 0.f; }
    float dv = D1[c];
    float pacc = 0.f;
    for (int t = 0; t < NRR; t++){
        int o = (b*NRR + t)*NRR + c;
        float dtv = dt1[o], xv = x1[o];
        float dx = dtv * xv;
        const float* bt = BT1 + (size_t)(b*NRR + t)*DST;
        const float* ct = CT1 + (size_t)(b*NRR + t)*DST;
        float y = dv * xv;
        #pragma unroll
        for (int s = 0; s < DST; s++){
            h[s] = expf(dtv*a[s])*h[s] + dx*bt[s];
            y += h[s]*ct[s];
        }
        pacc += y;
    }
    pooled[id] = pacc * (1.f/NRR);
}
__global__ void k_out1(const float* pooled, const float* Wout1, float* out1){
    int id = blockIdx.x*256 + threadIdx.x;
    if (id >= NBW*SEQL) return;
    int k = id % SEQL; int bw = id / SEQL; int w = bw % NWW; int b = bw / NWW;
    float s = 0.f;
    for (int d = 0; d < NRR; d++) s += pooled[b*NRR + d] * Wout1[((size_t)w*NRR + d)*SEQL + k];
    out1[id] = s;
}

// ---- layernorm over SEQ per (b,w) row ----
__global__ void k_ln(const float* in, const float* g, const float* bta, float* out){
    __shared__ float row[SEQL];
    __shared__ float red[256];
    int r = blockIdx.x; int tid = threadIdx.x;
    const float* x = in + (size_t)r*SEQL;
    float s = 0.f;
    for (int i = tid; i < SEQL; i += 256){ float v = x[i]; row[i] = v; s += v; }
    red[tid] = s; __syncthreads();
    for (int st = 128; st > 0; st >>= 1){ if (tid < st) red[tid] += red[tid+st]; __syncthreads(); }
    float m = red[0] * (1.f/SEQL); __syncthreads();
    float vs = 0.f;
    for (int i = tid; i < SEQL; i += 256){ float d = row[i] - m; vs += d*d; }
    red[tid] = vs; __syncthreads();
    for (int st = 128; st > 0; st >>= 1){ if (tid < st) red[tid] += red[tid+st]; __syncthreads(); }
    float inv = 1.f / sqrtf(red[0]*(1.f/SEQL) + EPSW);
    for (int i = tid; i < SEQL; i += 256)
        out[(size_t)r*SEQL + i] = (row[i] - m)*inv*g[i] + bta[i];
}

__global__ void k_x2(const float* ga, const float* ff, float* x2){
    int id = blockIdx.x*256 + threadIdx.x;
    if (id >= NBW*SEQL) return;
    int within = id % SEQL; int q = within % WSS; int n = within / WSS;
    int bw = id / SEQL; int w = bw % NWW; int b = bw / NWW;
    const float* gr = ga + ((size_t)b*NRR + n)*NRR;
    const float* fr = ff + (size_t)(b*NWW + w)*SEQL + q;
    float s = 0.f;
    for (int m = 0; m < NRR; m++) s += gr[m] * fr[m*WSS];
    x2[id] = s;
}
__global__ void k_dt2(const float* x2, const float* Wdt2, float* dt2){
    int id = blockIdx.x*256 + threadIdx.x;
    if (id >= NBW*SEQL) return;
    int c = id % SEQL; int bt = id / SEQL;
    const float* xr = x2 + (size_t)bt*SEQL;
    float s = 0.f;
    #pragma unroll 4
    for (int m = 0; m < SEQL; m++) s += xr[m] * Wdt2[(size_t)m*SEQL + c];
    dt2[id] = softplus_f(s);
}
__global__ void k_btct2(const float* x2, const float* WB2, const float* WC2,
                        float* BT2, float* CT2){
    int id = blockIdx.x*256 + threadIdx.x;
    if (id >= NBW*DST) return;
    int s_ = id % DST; int bt = id / DST;
    const float* xr = x2 + (size_t)bt*SEQL;
    float sb = 0.f, sc = 0.f;
    for (int m = 0; m < SEQL; m++){ float v = xr[m]; sb += v*WB2[m*DST + s_]; sc += v*WC2[m*DST + s_]; }
    BT2[id] = sb; CT2[id] = sc;
}
__global__ void k_sscan2(const float* x2, const float* dt2, const float* BT2, const float* CT2,
                         const float* A2, const float* D2, float* y2){
    int id = blockIdx.x*256 + threadIdx.x;
    if (id >= BSZ*SEQL) return;
    int c = id % SEQL, b = id / SEQL;
    float a[DST], h[DST];
    #pragma unroll
    for (int s = 0; s < DST; s++){ a[s] = A2[c*DST + s]; h[s] = 0.f; }
    float dv = D2[c];
    for (int t = 0; t < NWW; t++){
        int o = (b*NWW + t)*SEQL + c;
        float dtv = dt2[o], xv = x2[o];
        float dx = dtv * xv;
        const float* bt = BT2 + (size_t)(b*NWW + t)*DST;
        const float* ct = CT2 + (size_t)(b*NWW + t)*DST;
        float y = dv * xv;
        #pragma unroll
        for (int s = 0; s < DST; s++){
            h[s] = expf(dtv*a[s])*h[s] + dx*bt[s];
            y += h[s]*ct[s];
        }
        y2[o] = y;
    }
}
__global__ void k_out2(const float* y2, const float* Wout2, float* out2){
    int id = blockIdx.x*256 + threadIdx.x;
    if (id >= NBW*SEQL) return;
    int k = id % SEQL; int bw = id / SEQL;
    const float* yr = y2 + (size_t)bw*SEQL;
    float s = 0.f;
    #pragma unroll 4
    for (int m = 0; m < SEQL; m++) s += yr[m] * Wout2[(size_t)m*SEQL + k];
    out2[id] = s;
}

// ---- gate + fusion ----
__global__ void k_gatefusion(const float* fr2, const float* tf, const float* W_gate,
                             const float* b_gate, float* fusion){
    int id = blockIdx.x*256 + threadIdx.x;
    if (id >= BSZ*NRR*EDD) return;
    int j = id % EDD; int n = (id / EDD) % NRR; int b = id / (EDD*NRR);
    float acc = b_gate[j];
    for (int w = 0; w < NWW; w++){
        const float* f2 = fr2 + (size_t)(b*NWW + w)*SEQL + n*WSS;
        const float* tp = tf  + (size_t)(b*NWW + w)*SEQL + n*WSS;
        const float* wg = W_gate + (size_t)(w*2*WSS)*EDD + j;
        #pragma unroll
        for (int q = 0; q < WSS; q++) acc += f2[q]*wg[q*EDD];
        #pragma unroll
        for (int q = 0; q < WSS; q++) acc += tp[q]*wg[(WSS+q)*EDD];
    }
    float gt = sigmoid_f(acc);
    int w_ = j / WSS, q_ = j % WSS;
    float fp = fr2[(size_t)(b*NWW + w_)*SEQL + n*WSS + q_];
    float tp = tf [(size_t)(b*NWW + w_)*SEQL + n*WSS + q_];
    fusion[id] = gt*fp + (1.f - gt)*tp;
}

// ---- router: LN(170) -> 4 logits -> top2 softmax gates ----
__global__ void k_gates(const float* fusion, const float* rg, const float* rb,
                        const float* Wr, const float* brr, float* gatesE){
    int bn = blockIdx.x; int lane = threadIdx.x;
    const float* x = fusion + (size_t)bn*EDD;
    bool v2ok = (lane + 128) < EDD;
    float v0 = x[lane];
    float v1 = x[lane + 64];
    float v2 = v2ok ? x[lane + 128] : 0.f;
    float s = v0 + v1 + v2;
    for (int o = 32; o > 0; o >>= 1) s += __shfl_xor(s, o, 64);
    float m = s * (1.f/EDD);
    float d0 = v0 - m, d1 = v1 - m, d2 = v2ok ? (v2 - m) : 0.f;
    float vs = d0*d0 + d1*d1 + d2*d2;
    for (int o = 32; o > 0; o >>= 1) vs += __shfl_xor(vs, o, 64);
    float inv = 1.f / sqrtf(vs*(1.f/EDD) + EPSW);
    float r0 = d0*inv*rg[lane] + rb[lane];
    float r1 = d1*inv*rg[lane+64] + rb[lane+64];
    float r2 = v2ok ? (d2*inv*rg[lane+128] + rb[lane+128]) : 0.f;
    float pl[4];
    #pragma unroll
    for (int e = 0; e < 4; e++){
        float p = r0*Wr[lane*4 + e] + r1*Wr[(lane+64)*4 + e];
        if (v2ok) p += r2*Wr[(lane+128)*4 + e];
        for (int o = 32; o > 0; o >>= 1) p += __shfl_xor(p, o, 64);
        pl[e] = p;
    }
    if (lane == 0){
        float lg[4];
        #pragma unroll
        for (int e = 0; e < 4; e++) lg[e] = pl[e] + brr[e];
        int i0 = 0;
        for (int e = 1; e < 4; e++) if (lg[e] > lg[i0]) i0 = e;
        int i1 = -1;
        for (int e = 0; e < 4; e++) if (e != i0 && (i1 < 0 || lg[e] > lg[i1])) i1 = e;
        float e1 = expf(lg[i1] - lg[i0]);
        float w0 = 1.f/(1.f + e1), w1 = e1/(1.f + e1);
        float g[4] = {0.f,0.f,0.f,0.f};
        g[i0] = w0; g[i1] = w1;
        #pragma unroll
        for (int e = 0; e < 4; e++) gatesE[bn*4 + e] = g[e];
    }
}

__global__ void k_support(const float* fusion, const float* We, float* support){
    int id = blockIdx.x*256 + threadIdx.x;
    if (id >= BSZ*4*NRR*EDD) return;
    int g = id % EDD; int n = (id / EDD) % NRR; int e = (id / (EDD*NRR)) % 4; int b = id / (EDD*NRR*4);
    const float* fu = fusion + ((size_t)b*NRR + n)*EDD;
    const float* w = We + (size_t)e*EDD*EDD + g;
    float s = 0.f;
    for (int f = 0; f < EDD; f++) s += fu[f] * w[(size_t)f*EDD];
    support[id] = s;
}
__global__ void k_eout(const float* ga, const float* support, float* eout){
    int id = blockIdx.x*256 + threadIdx.x;
    if (id >= BSZ*4*NRR*EDD) return;
    int g = id % EDD; int n = (id / EDD) % NRR; int e = (id / (EDD*NRR)) % 4; int b = id / (EDD*NRR*4);
    const float* gr = ga + ((size_t)b*NRR + n)*NRR;
    const float* sp = support + ((size_t)(b*4 + e)*NRR)*EDD + g;
    float s = 0.f;
    for (int m = 0; m < NRR; m++) s += gr[m] * sp[(size_t)m*EDD];
    eout[id] = fmaxf(s, 0.f);
}
__global__ void k_moe(const float* eout, const float* gatesE, float* moe){
    int id = blockIdx.x*256 + threadIdx.x;
    if (id >= BSZ*NRR*EDD) return;
    int g = id % EDD; int n = (id / EDD) % NRR; int b = id / (EDD*NRR);
    const float* gt = gatesE + ((size_t)b*NRR + n)*4;
    float s = 0.f;
    #pragma unroll
    for (int e = 0; e < 4; e++)
        s += eout[((size_t)(b*4 + e)*NRR + n)*EDD + g] * gt[e];
    moe[id] = s;
}

#define MLPK (NRR*EDD)   // 19720
#define KSPLIT 16
#define KCH 1233
__global__ void k_mlp1p(const float* moe, const float* W1, float* part1){
    int id = blockIdx.x*256 + threadIdx.x;
    if (id >= KSPLIT*BSZ*512) return;
    int j = id % 512; int b = (id / 512) % BSZ; int kc = id / (512*BSZ);
    int i0 = kc*KCH; int i1 = i0 + KCH; if (i1 > MLPK) i1 = MLPK;
    const float* mo = moe + (size_t)b*MLPK;
    float s = 0.f;
    for (int i = i0; i < i1; i++) s += mo[i] * W1[(size_t)i*512 + j];
    part1[id] = s;
}
__global__ void k_mlp1c(const float* part1, const float* b1, float* h1){
    int id = blockIdx.x*256 + threadIdx.x;
    if (id >= BSZ*512) return;
    float s = 0.f;
    #pragma unroll
    for (int kc = 0; kc < KSPLIT; kc++) s += part1[(size_t)kc*BSZ*512 + id];
    const float sc = 0.99999500003750f; // 1/sqrt(1+1e-5)
    h1[id] = fmaxf((s + b1[id % 512]) * sc, 0.f);
}
__global__ void k_mlp2(const float* h1, const float* W2, const float* b2, float* h2){
    int id = blockIdx.x*256 + threadIdx.x;
    if (id >= BSZ*256) return;
    int j = id % 256; int b = id / 256;
    const float* h = h1 + (size_t)b*512;
    float s = 0.f;
    for (int i = 0; i < 512; i++) s += h[i] * W2[(size_t)i*256 + j];
    const float sc = 0.99999500003750f;
    h2[id] = fmaxf((s + b2[j]) * sc, 0.f);
}
__global__ void k_mlp3(const float* h2, const float* W3, const float* b3, float* h3){
    int id = blockIdx.x*256 + threadIdx.x;
    if (id >= BSZ*128) return;
    int j = id % 128; int b = id / 128;
    const float* h = h2 + (size_t)b*256;
    float s = 0.f;
    for (int i = 0; i < 256; i++) s += h[i] * W3[(size_t)i*128 + j];
    const float sc = 0.99999500003750f;
    h3[id] = fmaxf((s + b3[j]) * sc, 0.f);
}
__global__ void k_mlp4(const float* h3, const float* W4, const float* b4, float* out){
    int id = threadIdx.x;
    if (id >= BSZ*2) return;
    int o = id % 2; int b = id / 2;
    const float* h = h3 + (size_t)b*128;
    float s = 0.f;
    for (int i = 0; i < 128; i++) s += h[i] * W4[i*2 + o];
    out[id] = s + b4[o];
}

extern "C" void kernel_launch(void* const* d_in, const int* in_sizes, int n_in,
                              void* d_out, int out_size, void* d_ws, size_t ws_size,
                              hipStream_t stream){
    (void)in_sizes; (void)n_in; (void)out_size;
    const float* win_seq = (const float*)d_in[0];
    const float* win_pcc = (const float*)d_in[1];
    const float* ga      = (const float*)d_in[2];
    const float* emb     = (const float*)d_in[4];
    const float* fgc_w   = (const float*)d_in[5];
    const float* fgc_b   = (const float*)d_in[6];
    const float* w_c     = (const float*)d_in[7];
    const float* ln_g    = (const float*)d_in[8];
    const float* ln_b    = (const float*)d_in[9];
    const float* A1      = (const float*)d_in[10];
    const float* WB1     = (const float*)d_in[11];
    const float* WC1     = (const float*)d_in[12];
    const float* Wdt1    = (const float*)d_in[13];
    const float* D1      = (const float*)d_in[14];
    const float* Wout1   = (const float*)d_in[15];
    const float* A2      = (const float*)d_in[16];
    const float* WB2     = (const float*)d_in[17];
    const float* WC2     = (const float*)d_in[18];
    const float* Wdt2    = (const float*)d_in[19];
    const float* D2      = (const float*)d_in[20];
    const float* Wout2   = (const float*)d_in[21];
    const float* W_gate  = (const float*)d_in[22];
    const float* b_gate  = (const float*)d_in[23];
    const float* rln_g   = (const float*)d_in[24];
    const float* rln_b   = (const float*)d_in[25];
    const float* Wr      = (const float*)d_in[26];
    const float* brr     = (const float*)d_in[27];
    const float* We      = (const float*)d_in[28];
    const float* W1      = (const float*)d_in[29];
    const float* b1      = (const float*)d_in[30];
    const float* W2      = (const float*)d_in[31];
    const float* b2      = (const float*)d_in[32];
    const float* W3      = (const float*)d_in[33];
    const float* b3      = (const float*)d_in[34];
    const float* W4      = (const float*)d_in[35];
    const float* b4      = (const float*)d_in[36];
    float* out = (float*)d_out;
    float* ws  = (float*)d_ws;

    size_t off = 0;
    auto alloc = [&](size_t n){ size_t o = off; off += (n + 63) & ~(size_t)63; return o; };
    size_t o_tabc = alloc(SEQL), o_tabs = alloc(SEQL);
    size_t o_Ct = alloc((size_t)SEQL*FRQ), o_St = alloc((size_t)SEQL*FRQ);
    size_t o_Cf = alloc((size_t)SEQL*FRQ), o_Sf = alloc((size_t)SEQL*FRQ);
    size_t o_wcs = alloc(NWW*EMB);
    size_t o_ewr = alloc(NWW*EMB), o_ewi = alloc(NWW*EMB);
    size_t o_wre = alloc((size_t)NBW*FRQ), o_wim = alloc((size_t)NBW*FRQ);
    size_t o_wthi = alloc((size_t)1114112);   // 2,228,224 fp16 = 17*4*2*16384
    size_t o_wtlo = alloc((size_t)1114112);
    size_t o_zre = alloc((size_t)NBW*FRQ), o_zim = alloc((size_t)NBW*FRQ);
    size_t o_ff  = alloc((size_t)NBW*SEQL);
    size_t o_x1  = alloc((size_t)BSZ*NRR*NRR);
    size_t o_dt1 = alloc((size_t)BSZ*NRR*NRR);
    size_t o_BT1 = alloc((size_t)BSZ*NRR*DST), o_CT1 = alloc((size_t)BSZ*NRR*DST);
    size_t o_pool= alloc((size_t)BSZ*NRR);
    size_t o_o1  = alloc((size_t)NBW*SEQL);
    size_t o_tf  = alloc((size_t)NBW*SEQL);
    size_t o_x2  = alloc((size_t)NBW*SEQL);
    size_t o_dt2 = alloc((size_t)NBW*SEQL);
    size_t o_BT2 = alloc((size_t)NBW*DST), o_CT2 = alloc((size_t)NBW*DST);
    size_t o_y2  = alloc((size_t)NBW*SEQL);
    size_t o_o2  = alloc((size_t)NBW*SEQL);
    size_t o_fr2 = alloc((size_t)NBW*SEQL);
    size_t o_fus = alloc((size_t)BSZ*NRR*EDD);
    size_t o_gte = alloc((size_t)BSZ*NRR*4);
    size_t o_sup = alloc((size_t)BSZ*4*NRR*EDD);
    size_t o_eo  = alloc((size_t)BSZ*4*NRR*EDD);
    size_t o_moe = alloc((size_t)BSZ*NRR*EDD);
    size_t o_p1  = alloc((size_t)KSPLIT*BSZ*512);
    size_t o_h1  = alloc((size_t)BSZ*512);
    size_t o_h2  = alloc((size_t)BSZ*256);
    size_t o_h3  = alloc((size_t)BSZ*128);
    if (ws_size < off*sizeof(float)) return; // workspace too small -> visible failure

    #define WSP(o) (ws + (o))
    int nMk = (SEQL*FRQ + 255)/256;
    k_tables<<<(SEQL+255)/256, 256, 0, stream>>>(WSP(o_tabc), WSP(o_tabs));
    k_mk_tmaj<<<nMk, 256, 0, stream>>>(WSP(o_tabc), WSP(o_tabs), WSP(o_Ct), WSP(o_St));
    k_mk_fmaj<<<nMk, 256, 0, stream>>>(WSP(o_tabc), WSP(o_tabs), WSP(o_Cf), WSP(o_Sf));
    k_wcsm<<<NWW, EMB, 0, stream>>>(w_c, WSP(o_wcs));
    k_ew<<<(NWW*EMB+255)/256, 256, 0, stream>>>(emb, fgc_w, WSP(o_ewr), WSP(o_ewi));
    k_wprep<<<544, 256, 0, stream>>>(fgc_w, (_Float16*)WSP(o_wthi), (_Float16*)WSP(o_wtlo));
    k_dft<<<(NBW*FRQ+255)/256, 256, 0, stream>>>(win_seq, WSP(o_Ct), WSP(o_St), WSP(o_wre), WSP(o_wim));
    k_fgc_fused<<<dim3(19, NBW), 256, 0, stream>>>(WSP(o_wre), WSP(o_wim), WSP(o_ewr), WSP(o_ewi),
                                                   fgc_b, WSP(o_wcs),
                                                   (const _Float16*)WSP(o_wthi), (const _Float16*)WSP(o_wtlo),
                                                   WSP(o_zre), WSP(o_zim));
    k_irfft<<<(NBW*SEQL+255)/256, 256, 0, stream>>>(WSP(o_zre), WSP(o_zim), WSP(o_Cf), WSP(o_Sf), WSP(o_ff));
    // branch 1: pcc -> sscan1 -> out1 -> LN
    k_x1mean<<<(BSZ*NRR*NRR+255)/256, 256, 0, stream>>>(win_pcc, WSP(o_x1));
    k_dt1<<<(BSZ*NRR*NRR+255)/256, 256, 0, stream>>>(WSP(o_x1), Wdt1, WSP(o_dt1));
    k_btct1<<<(BSZ*NRR*DST+255)/256, 256, 0, stream>>>(WSP(o_x1), WB1, WC1, WSP(o_BT1), WSP(o_CT1));
    k_sscan1<<<(BSZ*NRR+255)/256, 256, 0, stream>>>(WSP(o_x1), WSP(o_dt1), WSP(o_BT1), WSP(o_CT1),
                                                    A1, D1, WSP(o_pool));
    k_out1<<<(NBW*SEQL+255)/256, 256, 0, stream>>>(WSP(o_pool), Wout1, WSP(o_o1));
    k_ln<<<NBW, 256, 0, stream>>>(WSP(o_o1), ln_g, ln_b, WSP(o_tf));
    // branch 2: freq_feat -> adj -> sscan2 -> out2 -> LN
    k_x2<<<(NBW*SEQL+255)/256, 256, 0, stream>>>(ga, WSP(o_ff), WSP(o_x2));
    k_dt2<<<(NBW*SEQL+255)/256, 256, 0, stream>>>(WSP(o_x2), Wdt2, WSP(o_dt2));
    k_btct2<<<(NBW*DST+255)/256, 256, 0, stream>>>(WSP(o_x2), WB2, WC2, WSP(o_BT2), WSP(o_CT2));
    k_sscan2<<<(BSZ*SEQL+255)/256, 256, 0, stream>>>(WSP(o_x2), WSP(o_dt2), WSP(o_BT2), WSP(o_CT2),
                                                     A2, D2, WSP(o_y2));
    k_out2<<<(NBW*SEQL+255)/256, 256, 0, stream>>>(WSP(o_y2), Wout2, WSP(o_o2));
    k_ln<<<NBW, 256, 0, stream>>>(WSP(o_o2), ln_g, ln_b, WSP(o_fr2));
    // fusion + MoE + MLP
    k_gatefusion<<<(BSZ*NRR*EDD+255)/256, 256, 0, stream>>>(WSP(o_fr2), WSP(o_tf), W_gate, b_gate, WSP(o_fus));
    k_gates<<<BSZ*NRR, 64, 0, stream>>>(WSP(o_fus), rln_g, rln_b, Wr, brr, WSP(o_gte));
    k_support<<<(BSZ*4*NRR*EDD+255)/256, 256, 0, stream>>>(WSP(o_fus), We, WSP(o_sup));
    k_eout<<<(BSZ*4*NRR*EDD+255)/256, 256, 0, stream>>>(ga, WSP(o_sup), WSP(o_eo));
    k_moe<<<(BSZ*NRR*EDD+255)/256, 256, 0, stream>>>(WSP(o_eo), WSP(o_gte), WSP(o_moe));
    k_mlp1p<<<(KSPLIT*BSZ*512)/256, 256, 0, stream>>>(WSP(o_moe), W1, WSP(o_p1));
    k_mlp1c<<<(BSZ*512)/256, 256, 0, stream>>>(WSP(o_p1), b1, WSP(o_h1));
    k_mlp2<<<(BSZ*256)/256, 256, 0, stream>>>(WSP(o_h1), W2, b2, WSP(o_h2));
    k_mlp3<<<(BSZ*128+255)/256, 256, 0, stream>>>(WSP(o_h2), W3, b3, WSP(o_h3));
    k_mlp4<<<1, 64, 0, stream>>>(WSP(o_h3), W4, b4, out);
    #undef WSP
}

// Round 3
// 2053.628 us; speedup vs baseline: 1.8530x; 1.1173x over previous
//
#include <hip/hip_runtime.h>
#include <math.h>

#define BSZ 16
#define NWW 17
#define NRR 116
#define WSS 10
#define EMB 128
#define LAYN 5
#define DST 16
#define SEQL 1160
#define FRQ 581
#define EDD 170
#define LAMW 0.01f
#define EPSW 1e-5f
#define NBW (BSZ*NWW)     // 272

// split-precision scales for f16 MFMA emulation of fp32 GEMM
#define SXF 1024.0f              // X scale (2^10)
#define SWF 4096.0f              // W scale (2^12)
#define INVS 2.384185791015625e-07f  // 1/(SXF*SWF) = 2^-22

typedef _Float16 half8 __attribute__((ext_vector_type(8)));
typedef float float4v __attribute__((ext_vector_type(4)));

__device__ __forceinline__ float softplus_f(float x){
    return fmaxf(x, 0.f) + log1pf(expf(-fabsf(x)));
}
__device__ __forceinline__ float sigmoid_f(float x){
    return 1.f / (1.f + expf(-x));
}

// ---- trig tables: tab[k] = cos/sin(2*pi*k/SEQL), double precision ----
__global__ void k_tables(float* tc, float* ts){
    int k = blockIdx.x*256 + threadIdx.x;
    if (k < SEQL){
        double th = (6.283185307179586476925286766559 * (double)k) / (double)SEQL;
        tc[k] = (float)cos(th);
        ts[k] = (float)sin(th);
    }
}
// DFT matrices, t-major (for forward) and f-major (for inverse)
__global__ void k_mk_tmaj(const float* tc, const float* ts, float* Ct, float* St){
    int id = blockIdx.x*256 + threadIdx.x;
    if (id >= SEQL*FRQ) return;
    int f = id % FRQ, t = id / FRQ;
    int idx = (f*t) % SEQL;
    Ct[id] = tc[idx]; St[id] = ts[idx];
}
__global__ void k_mk_fmaj(const float* tc, const float* ts, float* Cf, float* Sf){
    int id = blockIdx.x*256 + threadIdx.x;
    if (id >= SEQL*FRQ) return;
    int t = id % SEQL, f = id / SEQL;
    int idx = (f*t) % SEQL;
    Cf[id] = tc[idx]; Sf[id] = ts[idx];
}

// ---- softmax over w_c rows ----
__global__ void k_wcsm(const float* w_c, float* wcs){
    int w = blockIdx.x; int j = threadIdx.x;
    __shared__ float red[EMB];
    float v = w_c[w*EMB + j];
    red[j] = v; __syncthreads();
    for (int s = 64; s > 0; s >>= 1){ if (j < s) red[j] = fmaxf(red[j], red[j+s]); __syncthreads(); }
    float m = red[0]; __syncthreads();
    float e = expf(v - m);
    red[j] = e; __syncthreads();
    for (int s = 64; s > 0; s >>= 1){ if (j < s) red[j] += red[j+s]; __syncthreads(); }
    wcs[w*EMB + j] = e / red[0];
}

// ---- ew[w,j] = sum_i emb[i] * fgc_w[w,0,ri,i,j] ----
__global__ void k_ew(const float* emb, const float* fgc_w, float* ewr, float* ewi){
    int id = blockIdx.x*256 + threadIdx.x;
    if (id >= NWW*EMB) return;
    int w = id / EMB, j = id % EMB;
    const float* wr = fgc_w + ((size_t)(w*LAYN + 0)*2 + 0)*EMB*EMB;
    const float* wi = wr + (size_t)EMB*EMB;
    float ar = 0.f, ai = 0.f;
    for (int i = 0; i < EMB; i++){
        float e = emb[i];
        ar += e * wr[i*EMB + j];
        ai += e * wi[i*EMB + j];
    }
    ewr[id] = ar; ewi[id] = ai;
}

// ---- forward DFT of win_seq rows, 4 bw per block, win_seq staged in LDS ----
__global__ void k_dft(const float* ws, const float* Ct, const float* St,
                      float* wre, float* wim){
    __shared__ float X[4][SEQL];
    int f = blockIdx.x*256 + threadIdx.x;   // grid.x = 3
    int bw0 = blockIdx.y*4;                 // grid.y = 68
    for (int e = threadIdx.x; e < 4*SEQL; e += 256){
        int g = e / SEQL, t = e % SEQL;
        X[g][t] = ws[(size_t)(bw0+g)*SEQL + t];
    }
    __syncthreads();
    if (f >= FRQ) return;
    float sr[4] = {0,0,0,0}, si[4] = {0,0,0,0};
    #pragma unroll 2
    for (int t = 0; t < SEQL; t++){
        float ct_ = Ct[(size_t)t*FRQ + f];
        float st_ = St[(size_t)t*FRQ + f];
        #pragma unroll
        for (int g = 0; g < 4; g++){
            sr[g] += X[g][t]*ct_;
            si[g] += X[g][t]*st_;
        }
    }
    const float sc = 0.02936128f; // 1/sqrt(1160)
    #pragma unroll
    for (int g = 0; g < 4; g++){
        wre[(size_t)(bw0+g)*FRQ + f] = sr[g]*sc;
        wim[(size_t)(bw0+g)*FRQ + f] = -si[g]*sc;
    }
}

// ---- weight prep: transpose + scale + fp16 hi/lo split, packed in MFMA fragment
// order so the GEMM kernel's loads are wave-contiguous (1 KB per instruction).
// Wpk[wl=w*4+lm1][p=hiR,loR,hiI,loI][nb=0..7][kc=0..3][lane=q*16+c][j=0..7]
// element = W^T[n=nb*16+c][k=kc*32+q*8+j] * SWF
__global__ void k_wprep(const float* fgc_w, _Float16* Wpk){
    __shared__ float T[128][129];
    int blk = blockIdx.x;              // 0..135
    int ri = blk & 1; int wl = blk >> 1;    // wl = w*4 + lm1
    int w = wl >> 2; int lm1 = wl & 3;
    const float* src = fgc_w + ((size_t)(w*LAYN + lm1+1)*2 + ri)*EMB*EMB;
    for (int e = threadIdx.x; e < 16384; e += 256){
        int i = e >> 7, j = e & 127;
        T[i][j] = src[e] * SWF;
    }
    __syncthreads();
    size_t base = (size_t)wl*65536;
    _Float16* hi = Wpk + base + (size_t)(2*ri)*16384;
    _Float16* lo = Wpk + base + (size_t)(2*ri+1)*16384;
    for (int c8 = 0; c8 < 8; c8++){
        int d0 = c8*2048 + threadIdx.x*8;
        int nb = d0 >> 11; int rem = d0 & 2047;
        int kc = rem >> 9; int l = (rem & 511) >> 3;
        int q = l >> 4, cc = l & 15;
        int n = nb*16 + cc;
        half8 hv, lv;
        #pragma unroll
        for (int jj = 0; jj < 8; jj++){
            int k = kc*32 + q*8 + jj;
            float v = T[k][n];
            _Float16 h = (_Float16)v;
            hv[jj] = h; lv[jj] = (_Float16)(v - (float)h);
        }
        *(half8*)&hi[d0] = hv;
        *(half8*)&lo[d0] = lv;
    }
}

// ---- fused FGC: layer0 (rank-1) + 4 complex GEMM layers (f16 split MFMA) + zred ----
#define ALD 140   // A-plane row stride in halfs (70 words == 6 mod 32: no c/q aliasing)
__launch_bounds__(256, 3)
__global__ void k_fgc_fused(const float* wre, const float* wim,
                            const float* ewr, const float* ewi,
                            const float* fgc_b, const float* wcs,
                            const _Float16* Wpk,
                            float* zre, float* zim){
    __shared__ _Float16 AhR[32*ALD];
    __shared__ _Float16 AlR[32*ALD];
    __shared__ _Float16 AhI[32*ALD];
    __shared__ _Float16 AlI[32*ALD];
    __shared__ float OUTR[16*130];
    __shared__ float OUTI[16*130];
    int tid = threadIdx.x;
    int bw = blockIdx.y; int w = bw % NWW;
    int f0 = blockIdx.x * 32;
    int lane = tid & 63, wv = tid >> 6;
    int c = lane & 15, q = lane >> 4;

    // ---- layer 0: X0[f][j] = relu(wre*ewr - wim*ewi + br - lam), split to LDS ----
    {
        int f = tid >> 3;            // 0..31
        int j0 = (tid & 7) << 4;     // 0..112
        int fg = f0 + f;
        float re = 0.f, im = 0.f;
        if (fg < FRQ){ re = wre[(size_t)bw*FRQ + fg]; im = wim[(size_t)bw*FRQ + fg]; }
        const float* br = fgc_b + (size_t)(w*LAYN + 0)*2*EMB;
        const float* bi = br + EMB;
        #pragma unroll
        for (int g = 0; g < 2; g++){
            half8 hR, lR, hI, lI;
            #pragma unroll
            for (int u = 0; u < 8; u++){
                int jj = j0 + g*8 + u;
                float er = ewr[w*EMB + jj], ei = ewi[w*EMB + jj];
                float xr = fmaxf(re*er - im*ei + br[jj] - LAMW, 0.f) * SXF;
                float xi = fmaxf(im*er + re*ei + bi[jj] - LAMW, 0.f) * SXF;
                _Float16 h1 = (_Float16)xr; hR[u] = h1; lR[u] = (_Float16)(xr - (float)h1);
                _Float16 h2 = (_Float16)xi; hI[u] = h2; lI[u] = (_Float16)(xi - (float)h2);
            }
            int ao = f*ALD + j0 + g*8;
            *(half8*)&AhR[ao] = hR;
            *(half8*)&AlR[ao] = lR;
            *(half8*)&AhI[ao] = hI;
            *(half8*)&AlI[ao] = lI;
        }
    }
    __syncthreads();

    for (int l = 1; l <= 4; l++){
        const _Float16* Wb = Wpk + (size_t)(w*4 + (l-1))*65536;
        float4v Prr[2][2], Pii[2][2], Pri[2][2], Pir[2][2];
        #pragma unroll
        for (int rt = 0; rt < 2; rt++)
            #pragma unroll
            for (int ct = 0; ct < 2; ct++){
                #pragma unroll
                for (int u = 0; u < 4; u++){
                    Prr[rt][ct][u] = 0.f; Pii[rt][ct][u] = 0.f;
                    Pri[rt][ct][u] = 0.f; Pir[rt][ct][u] = 0.f;
                }
            }
        for (int kc = 0; kc < 4; kc++){
            int ko = kc*32 + q*8;
            half8 ahR[2], alR[2], ahI[2], alI[2];
            #pragma unroll
            for (int rt = 0; rt < 2; rt++){
                int ao = (rt*16 + c)*ALD + ko;
                ahR[rt] = *(const half8*)&AhR[ao];
                alR[rt] = *(const half8*)&AlR[ao];
                ahI[rt] = *(const half8*)&AhI[ao];
                alI[rt] = *(const half8*)&AlI[ao];
            }
            #pragma unroll
            for (int ct = 0; ct < 2; ct++){
                int off = ((wv*2 + ct)*2048) + kc*512 + lane*8;  // wave-contiguous
                half8 whR = *(const half8*)&Wb[off];
                half8 wlR = *(const half8*)&Wb[16384 + off];
                half8 whI = *(const half8*)&Wb[32768 + off];
                half8 wlI = *(const half8*)&Wb[49152 + off];
                #pragma unroll
                for (int rt = 0; rt < 2; rt++){
                    // Ar*Wr
                    Prr[rt][ct] = __builtin_amdgcn_mfma_f32_16x16x32_f16(ahR[rt], whR, Prr[rt][ct], 0,0,0);
                    Prr[rt][ct] = __builtin_amdgcn_mfma_f32_16x16x32_f16(ahR[rt], wlR, Prr[rt][ct], 0,0,0);
                    Prr[rt][ct] = __builtin_amdgcn_mfma_f32_16x16x32_f16(alR[rt], whR, Prr[rt][ct], 0,0,0);
                    // Ai*Wi
                    Pii[rt][ct] = __builtin_amdgcn_mfma_f32_16x16x32_f16(ahI[rt], whI, Pii[rt][ct], 0,0,0);
                    Pii[rt][ct] = __builtin_amdgcn_mfma_f32_16x16x32_f16(ahI[rt], wlI, Pii[rt][ct], 0,0,0);
                    Pii[rt][ct] = __builtin_amdgcn_mfma_f32_16x16x32_f16(alI[rt], whI, Pii[rt][ct], 0,0,0);
                    // Ar*Wi
                    Pri[rt][ct] = __builtin_amdgcn_mfma_f32_16x16x32_f16(ahR[rt], whI, Pri[rt][ct], 0,0,0);
                    Pri[rt][ct] = __builtin_amdgcn_mfma_f32_16x16x32_f16(ahR[rt], wlI, Pri[rt][ct], 0,0,0);
                    Pri[rt][ct] = __builtin_amdgcn_mfma_f32_16x16x32_f16(alR[rt], whI, Pri[rt][ct], 0,0,0);
                    // Ai*Wr
                    Pir[rt][ct] = __builtin_amdgcn_mfma_f32_16x16x32_f16(ahI[rt], whR, Pir[rt][ct], 0,0,0);
                    Pir[rt][ct] = __builtin_amdgcn_mfma_f32_16x16x32_f16(ahI[rt], wlR, Pir[rt][ct], 0,0,0);
                    Pir[rt][ct] = __builtin_amdgcn_mfma_f32_16x16x32_f16(alI[rt], whR, Pir[rt][ct], 0,0,0);
                }
            }
        }
        __syncthreads();   // all waves done reading A planes
        const float* bR = fgc_b + (size_t)(w*LAYN + l)*2*EMB;
        const float* bI = bR + EMB;
        #pragma unroll
        for (int chunk = 0; chunk < 2; chunk++){
            // epilogue: rows chunk*16..+16, this wave's 32 cols (D: col=lane&15, row=q*4+reg)
            #pragma unroll
            for (int ct = 0; ct < 2; ct++){
                int n = wv*32 + ct*16 + c;
                float biasR = bR[n] - LAMW, biasI = bI[n] - LAMW;
                #pragma unroll
                for (int r = 0; r < 4; r++){
                    int row = q*4 + r;
                    float vR = (Prr[chunk][ct][r] - Pii[chunk][ct][r])*INVS + biasR;
                    float vI = (Pir[chunk][ct][r] + Pri[chunk][ct][r])*INVS + biasI;
                    OUTR[row*130 + n] = fmaxf(vR, 0.f);
                    OUTI[row*130 + n] = fmaxf(vI, 0.f);
                }
            }
            __syncthreads();
            if (l < 4){
                // repack chunk into A planes (split to fp16 hi/lo, scaled)
                int fch = tid >> 4;            // 0..15
                int j0r = (tid & 15) << 3;     // 0..120
                half8 hR, lR, hI, lI;
                #pragma unroll
                for (int u = 0; u < 8; u++){
                    float xr = OUTR[fch*130 + j0r + u] * SXF;
                    float xi = OUTI[fch*130 + j0r + u] * SXF;
                    _Float16 h1 = (_Float16)xr; hR[u] = h1; lR[u] = (_Float16)(xr - (float)h1);
                    _Float16 h2 = (_Float16)xi; hI[u] = h2; lI[u] = (_Float16)(xi - (float)h2);
                }
                int ao = (chunk*16 + fch)*ALD + j0r;
                *(half8*)&AhR[ao] = hR;
                *(half8*)&AlR[ao] = lR;
                *(half8*)&AhI[ao] = hI;
                *(half8*)&AlI[ao] = lI;
            } else {
                // final layer: contract with softmaxed w_c over EMB -> zre/zim
                int fch = tid >> 4;
                int j0r = (tid & 15) << 3;
                float sR = 0.f, sI = 0.f;
                #pragma unroll
                for (int u = 0; u < 8; u++){
                    float cwc = wcs[w*EMB + j0r + u];
                    sR += OUTR[fch*130 + j0r + u] * cwc;
                    sI += OUTI[fch*130 + j0r + u] * cwc;
                }
                #pragma unroll
                for (int o = 8; o > 0; o >>= 1){
                    sR += __shfl_down(sR, o, 64);
                    sI += __shfl_down(sI, o, 64);
                }
                int fg = f0 + chunk*16 + fch;
                if ((tid & 15) == 0 && fg < FRQ){
                    zre[(size_t)bw*FRQ + fg] = sR;
                    zim[(size_t)bw*FRQ + fg] = sI;
                }
            }
            __syncthreads();
        }
    }
}

// ---- inverse DFT, 4 bw per block, z staged in LDS ----
__global__ void k_irfft(const float* zre, const float* zim, const float* Cf, const float* Sf,
                        float* ff){
    __shared__ float ZR[4][FRQ];
    __shared__ float ZI[4][FRQ];
    int t = blockIdx.x*256 + threadIdx.x;   // grid.x = 5
    int bw0 = blockIdx.y*4;                 // grid.y = 68
    for (int e = threadIdx.x; e < 4*FRQ; e += 256){
        int g = e / FRQ, f = e % FRQ;
        ZR[g][f] = zre[(size_t)(bw0+g)*FRQ + f];
        ZI[g][f] = zim[(size_t)(bw0+g)*FRQ + f];
    }
    __syncthreads();
    if (t >= SEQL) return;
    float acc[4] = {0,0,0,0};
    #pragma unroll 2
    for (int f = 1; f < FRQ-1; f++){
        float cf = Cf[(size_t)f*SEQL + t];
        float sf = Sf[(size_t)f*SEQL + t];
        #pragma unroll
        for (int g = 0; g < 4; g++)
            acc[g] += ZR[g][f]*cf - ZI[g][f]*sf;
    }
    float sgn = (t & 1) ? -1.f : 1.f;
    #pragma unroll
    for (int g = 0; g < 4; g++){
        float v = ZR[g][0] + 2.f*acc[g] + sgn*ZR[g][FRQ-1];
        ff[(size_t)(bw0+g)*SEQL + t] = v * 0.02936128f; // 1/sqrt(1160)
    }
}

// ---- x1 = mean over NW of win_pcc ----
__global__ void k_x1mean(const float* pcc, float* x1){
    int id = blockIdx.x*256 + threadIdx.x;
    if (id >= BSZ*NRR*NRR) return;
    const float* p = pcc + (size_t)id*NWW;
    float s = 0.f;
    for (int w = 0; w < NWW; w++) s += p[w];
    x1[id] = s * (1.f/NWW);
}

__global__ void k_dt1(const float* x1, const float* Wdt1, float* dt1){
    int id = blockIdx.x*256 + threadIdx.x;
    if (id >= BSZ*NRR*NRR) return;
    int c = id % NRR; int bt = id / NRR;
    const float* xr = x1 + (size_t)bt*NRR;
    float s = 0.f;
    for (int m = 0; m < NRR; m++) s += xr[m] * Wdt1[m*NRR + c];
    dt1[id] = softplus_f(s);
}
__global__ void k_btct1(const float* x1, const float* WB1, const float* WC1,
                        float* BT1, float* CT1){
    int id = blockIdx.x*256 + threadIdx.x;
    if (id >= BSZ*NRR*DST) return;
    int s_ = id % DST; int bt = id / DST;
    const float* xr = x1 + (size_t)bt*NRR;
    float sb = 0.f, sc = 0.f;
    for (int m = 0; m < NRR; m++){ float v = xr[m]; sb += v*WB1[m*DST + s_]; sc += v*WC1[m*DST + s_]; }
    BT1[id] = sb; CT1[id] = sc;
}
__global__ void k_sscan1(const float* x1, const float* dt1, const float* BT1, const float* CT1,
                         const float* A1, const float* D1, float* pooled){
    int id = blockIdx.x*256 + threadIdx.x;
    if (id >= BSZ*NRR) return;
    int c = id % NRR, b = id / NRR;
    float a[DST], h[DST];
    #pragma unroll
    for (int s = 0; s < DST; s++){ a[s] = A1[c*DST + s]; h[s] = 0.f; }
    float dv = D1[c];
    float pacc = 0.f;
    for (int t = 0; t < NRR; t++){
        int o = (b*NRR + t)*NRR + c;
        float dtv = dt1[o], xv = x1[o];
        float dx = dtv * xv;
        const float* bt = BT1 + (size_t)(b*NRR + t)*DST;
        const float* ct = CT1 + (size_t)(b*NRR + t)*DST;
        float y = dv * xv;
        #pragma unroll
        for (int s = 0; s < DST; s++){
            h[s] = expf(dtv*a[s])*h[s] + dx*bt[s];
            y += h[s]*ct[s];
        }
        pacc += y;
    }
    pooled[id] = pacc * (1.f/NRR);
}
__global__ void k_out1(const float* pooled, const float* Wout1, float* out1){
    int id = blockIdx.x*256 + threadIdx.x;
    if (id >= NBW*SEQL) return;
    int k = id % SEQL; int bw = id / SEQL; int w = bw % NWW; int b = bw / NWW;
    float s = 0.f;
    for (int d = 0; d < NRR; d++) s += pooled[b*NRR + d] * Wout1[((size_t)w*NRR + d)*SEQL + k];
    out1[id] = s;
}

// ---- layernorm over SEQ per (b,w) row ----
__global__ void k_ln(const float* in, const float* g, const float* bta, float* out){
    __shared__ float row[SEQL];
    __shared__ float red[256];
    int r = blockIdx.x; int tid = threadIdx.x;
    const float* x = in + (size_t)r*SEQL;
    float s = 0.f;
    for (int i = tid; i < SEQL; i += 256){ float v = x[i]; row[i] = v; s += v; }
    red[tid] = s; __syncthreads();
    for (int st = 128; st > 0; st >>= 1){ if (tid < st) red[tid] += red[tid+st]; __syncthreads(); }
    float m = red[0] * (1.f/SEQL); __syncthreads();
    float vs = 0.f;
    for (int i = tid; i < SEQL; i += 256){ float d = row[i] - m; vs += d*d; }
    red[tid] = vs; __syncthreads();
    for (int st = 128; st > 0; st >>= 1){ if (tid < st) red[tid] += red[tid+st]; __syncthreads(); }
    float inv = 1.f / sqrtf(red[0]*(1.f/SEQL) + EPSW);
    for (int i = tid; i < SEQL; i += 256)
        out[(size_t)r*SEQL + i] = (row[i] - m)*inv*g[i] + bta[i];
}

__global__ void k_x2(const float* ga, const float* ff, float* x2){
    int id = blockIdx.x*256 + threadIdx.x;
    if (id >= NBW*SEQL) return;
    int within = id % SEQL; int q = within % WSS; int n = within / WSS;
    int bw = id / SEQL; int w = bw % NWW; int b = bw / NWW;
    const float* gr = ga + ((size_t)b*NRR + n)*NRR;
    const float* fr = ff + (size_t)(b*NWW + w)*SEQL + q;
    float s = 0.f;
    for (int m = 0; m < NRR; m++) s += gr[m] * fr[m*WSS];
    x2[id] = s;
}
// ---- dt2: 4 rows per block, x2 rows staged in LDS ----
__global__ void k_dt2(const float* x2, const float* Wdt2, float* dt2){
    __shared__ float X[4][SEQL];
    int c = blockIdx.x*256 + threadIdx.x;   // grid.x = 5
    int bt0 = blockIdx.y*4;                 // grid.y = 68
    for (int e = threadIdx.x; e < 4*SEQL; e += 256){
        int g = e / SEQL, m = e % SEQL;
        X[g][m] = x2[(size_t)(bt0+g)*SEQL + m];
    }
    __syncthreads();
    if (c >= SEQL) return;
    float a[4] = {0,0,0,0};
    #pragma unroll 2
    for (int m = 0; m < SEQL; m++){
        float wv_ = Wdt2[(size_t)m*SEQL + c];
        #pragma unroll
        for (int g = 0; g < 4; g++) a[g] += X[g][m]*wv_;
    }
    #pragma unroll
    for (int g = 0; g < 4; g++)
        dt2[(size_t)(bt0+g)*SEQL + c] = softplus_f(a[g]);
}
__global__ void k_btct2(const float* x2, const float* WB2, const float* WC2,
                        float* BT2, float* CT2){
    int id = blockIdx.x*256 + threadIdx.x;
    if (id >= NBW*DST) return;
    int s_ = id % DST; int bt = id / DST;
    const float* xr = x2 + (size_t)bt*SEQL;
    float sb = 0.f, sc = 0.f;
    for (int m = 0; m < SEQL; m++){ float v = xr[m]; sb += v*WB2[m*DST + s_]; sc += v*WC2[m*DST + s_]; }
    BT2[id] = sb; CT2[id] = sc;
}
__global__ void k_sscan2(const float* x2, const float* dt2, const float* BT2, const float* CT2,
                         const float* A2, const float* D2, float* y2){
    int id = blockIdx.x*256 + threadIdx.x;
    if (id >= BSZ*SEQL) return;
    int c = id % SEQL, b = id / SEQL;
    float a[DST], h[DST];
    #pragma unroll
    for (int s = 0; s < DST; s++){ a[s] = A2[c*DST + s]; h[s] = 0.f; }
    float dv = D2[c];
    for (int t = 0; t < NWW; t++){
        int o = (b*NWW + t)*SEQL + c;
        float dtv = dt2[o], xv = x2[o];
        float dx = dtv * xv;
        const float* bt = BT2 + (size_t)(b*NWW + t)*DST;
        const float* ct = CT2 + (size_t)(b*NWW + t)*DST;
        float y = dv * xv;
        #pragma unroll
        for (int s = 0; s < DST; s++){
            h[s] = expf(dtv*a[s])*h[s] + dx*bt[s];
            y += h[s]*ct[s];
        }
        y2[o] = y;
    }
}
// ---- out2: 4 rows per block, y2 rows staged in LDS ----
__global__ void k_out2(const float* y2, const float* Wout2, float* out2){
    __shared__ float Y[4][SEQL];
    int k = blockIdx.x*256 + threadIdx.x;   // grid.x = 5
    int bw0 = blockIdx.y*4;                 // grid.y = 68
    for (int e = threadIdx.x; e < 4*SEQL; e += 256){
        int g = e / SEQL, m = e % SEQL;
        Y[g][m] = y2[(size_t)(bw0+g)*SEQL + m];
    }
    __syncthreads();
    if (k >= SEQL) return;
    float a[4] = {0,0,0,0};
    #pragma unroll 2
    for (int m = 0; m < SEQL; m++){
        float wv_ = Wout2[(size_t)m*SEQL + k];
        #pragma unroll
        for (int g = 0; g < 4; g++) a[g] += Y[g][m]*wv_;
    }
    #pragma unroll
    for (int g = 0; g < 4; g++)
        out2[(size_t)(bw0+g)*SEQL + k] = a[g];
}

// ---- gate + fusion ----
__global__ void k_gatefusion(const float* fr2, const float* tf, const float* W_gate,
                             const float* b_gate, float* fusion){
    int id = blockIdx.x*256 + threadIdx.x;
    if (id >= BSZ*NRR*EDD) return;
    int j = id % EDD; int n = (id / EDD) % NRR; int b = id / (EDD*NRR);
    float acc = b_gate[j];
    for (int w = 0; w < NWW; w++){
        const float* f2 = fr2 + (size_t)(b*NWW + w)*SEQL + n*WSS;
        const float* tp = tf  + (size_t)(b*NWW + w)*SEQL + n*WSS;
        const float* wg = W_gate + (size_t)(w*2*WSS)*EDD + j;
        #pragma unroll
        for (int q = 0; q < WSS; q++) acc += f2[q]*wg[q*EDD];
        #pragma unroll
        for (int q = 0; q < WSS; q++) acc += tp[q]*wg[(WSS+q)*EDD];
    }
    float gt = sigmoid_f(acc);
    int w_ = j / WSS, q_ = j % WSS;
    float fp = fr2[(size_t)(b*NWW + w_)*SEQL + n*WSS + q_];
    float tp = tf [(size_t)(b*NWW + w_)*SEQL + n*WSS + q_];
    fusion[id] = gt*fp + (1.f - gt)*tp;
}

// ---- router: LN(170) -> 4 logits -> top2 softmax gates ----
__global__ void k_gates(const float* fusion, const float* rg, const float* rb,
                        const float* Wr, const float* brr, float* gatesE){
    int bn = blockIdx.x; int lane = threadIdx.x;
    const float* x = fusion + (size_t)bn*EDD;
    bool v2ok = (lane + 128) < EDD;
    float v0 = x[lane];
    float v1 = x[lane + 64];
    float v2 = v2ok ? x[lane + 128] : 0.f;
    float s = v0 + v1 + v2;
    for (int o = 32; o > 0; o >>= 1) s += __shfl_xor(s, o, 64);
    float m = s * (1.f/EDD);
    float d0 = v0 - m, d1 = v1 - m, d2 = v2ok ? (v2 - m) : 0.f;
    float vs = d0*d0 + d1*d1 + d2*d2;
    for (int o = 32; o > 0; o >>= 1) vs += __shfl_xor(vs, o, 64);
    float inv = 1.f / sqrtf(vs*(1.f/EDD) + EPSW);
    float r0 = d0*inv*rg[lane] + rb[lane];
    float r1 = d1*inv*rg[lane+64] + rb[lane+64];
    float r2 = v2ok ? (d2*inv*rg[lane+128] + rb[lane+128]) : 0.f;
    float pl[4];
    #pragma unroll
    for (int e = 0; e < 4; e++){
        float p = r0*Wr[lane*4 + e] + r1*Wr[(lane+64)*4 + e];
        if (v2ok) p += r2*Wr[(lane+128)*4 + e];
        for (int o = 32; o > 0; o >>= 1) p += __shfl_xor(p, o, 64);
        pl[e] = p;
    }
    if (lane == 0){
        float lg[4];
        #pragma unroll
        for (int e = 0; e < 4; e++) lg[e] = pl[e] + brr[e];
        int i0 = 0;
        for (int e = 1; e < 4; e++) if (lg[e] > lg[i0]) i0 = e;
        int i1 = -1;
        for (int e = 0; e < 4; e++) if (e != i0 && (i1 < 0 || lg[e] > lg[i1])) i1 = e;
        float e1 = expf(lg[i1] - lg[i0]);
        float w0 = 1.f/(1.f + e1), w1 = e1/(1.f + e1);
        float g[4] = {0.f,0.f,0.f,0.f};
        g[i0] = w0; g[i1] = w1;
        #pragma unroll
        for (int e = 0; e < 4; e++) gatesE[bn*4 + e] = g[e];
    }
}

__global__ void k_support(const float* fusion, const float* We, float* support){
    int id = blockIdx.x*256 + threadIdx.x;
    if (id >= BSZ*4*NRR*EDD) return;
    int g = id % EDD; int n = (id / EDD) % NRR; int e = (id / (EDD*NRR)) % 4; int b = id / (EDD*NRR*4);
    const float* fu = fusion + ((size_t)b*NRR + n)*EDD;
    const float* w = We + (size_t)e*EDD*EDD + g;
    float s = 0.f;
    for (int f = 0; f < EDD; f++) s += fu[f] * w[(size_t)f*EDD];
    support[id] = s;
}
__global__ void k_eout(const float* ga, const float* support, float* eout){
    int id = blockIdx.x*256 + threadIdx.x;
    if (id >= BSZ*4*NRR*EDD) return;
    int g = id % EDD; int n = (id / EDD) % NRR; int e = (id / (EDD*NRR)) % 4; int b = id / (EDD*NRR*4);
    const float* gr = ga + ((size_t)b*NRR + n)*NRR;
    const float* sp = support + ((size_t)(b*4 + e)*NRR)*EDD + g;
    float s = 0.f;
    for (int m = 0; m < NRR; m++) s += gr[m] * sp[(size_t)m*EDD];
    eout[id] = fmaxf(s, 0.f);
}
__global__ void k_moe(const float* eout, const float* gatesE, float* moe){
    int id = blockIdx.x*256 + threadIdx.x;
    if (id >= BSZ*NRR*EDD) return;
    int g = id % EDD; int n = (id / EDD) % NRR; int b = id / (EDD*NRR);
    const float* gt = gatesE + ((size_t)b*NRR + n)*4;
    float s = 0.f;
    #pragma unroll
    for (int e = 0; e < 4; e++)
        s += eout[((size_t)(b*4 + e)*NRR + n)*EDD + g] * gt[e];
    moe[id] = s;
}

#define MLPK (NRR*EDD)   // 19720
#define KSPLIT 80
#define KCH 247
// mlp1: all 16 batch rows share one read of the W1 chunk; moe chunk staged in LDS
__global__ void k_mlp1p(const float* moe, const float* W1, float* part1){
    __shared__ float M[16*KCH];   // 15.8 KB
    int kc = blockIdx.x;          // 0..79
    int j = blockIdx.y*256 + threadIdx.x;  // grid.y = 2
    int i0 = kc*KCH; int len = MLPK - i0; if (len > KCH) len = KCH;
    for (int e = threadIdx.x; e < 16*len; e += 256){
        int b = e / len, i = e % len;
        M[b*KCH + i] = moe[(size_t)b*MLPK + i0 + i];
    }
    __syncthreads();
    float acc[16];
    #pragma unroll
    for (int b = 0; b < 16; b++) acc[b] = 0.f;
    for (int i = 0; i < len; i++){
        float wv_ = W1[(size_t)(i0+i)*512 + j];
        #pragma unroll
        for (int b = 0; b < 16; b++) acc[b] += M[b*KCH + i]*wv_;
    }
    #pragma unroll
    for (int b = 0; b < 16; b++)
        part1[((size_t)kc*BSZ + b)*512 + j] = acc[b];
}
__global__ void k_mlp1c(const float* part1, const float* b1, float* h1){
    int id = blockIdx.x*256 + threadIdx.x;
    if (id >= BSZ*512) return;
    float s = 0.f;
    for (int kc = 0; kc < KSPLIT; kc++) s += part1[(size_t)kc*BSZ*512 + id];
    const float sc = 0.99999500003750f; // 1/sqrt(1+1e-5)
    h1[id] = fmaxf((s + b1[id % 512]) * sc, 0.f);
}
__global__ void k_mlp2(const float* h1, const float* W2, const float* b2, float* h2){
    int id = blockIdx.x*256 + threadIdx.x;
    if (id >= BSZ*256) return;
    int j = id % 256; int b = id / 256;
    const float* h = h1 + (size_t)b*512;
    float s = 0.f;
    for (int i = 0; i < 512; i++) s += h[i] * W2[(size_t)i*256 + j];
    const float sc = 0.99999500003750f;
    h2[id] = fmaxf((s + b2[j]) * sc, 0.f);
}
__global__ void k_mlp3(const float* h2, const float* W3, const float* b3, float* h3){
    int id = blockIdx.x*256 + threadIdx.x;
    if (id >= BSZ*128) return;
    int j = id % 128; int b = id / 128;
    const float* h = h2 + (size_t)b*256;
    float s = 0.f;
    for (int i = 0; i < 256; i++) s += h[i] * W3[(size_t)i*128 + j];
    const float sc = 0.99999500003750f;
    h3[id] = fmaxf((s + b3[j]) * sc, 0.f);
}
__global__ void k_mlp4(const float* h3, const float* W4, const float* b4, float* out){
    int id = threadIdx.x;
    if (id >= BSZ*2) return;
    int o = id % 2; int b = id / 2;
    const float* h = h3 + (size_t)b*128;
    float s = 0.f;
    for (int i = 0; i < 128; i++) s += h[i] * W4[i*2 + o];
    out[id] = s + b4[o];
}

extern "C" void kernel_launch(void* const* d_in, const int* in_sizes, int n_in,
                              void* d_out, int out_size, void* d_ws, size_t ws_size,
                              hipStream_t stream){
    (void)in_sizes; (void)n_in; (void)out_size;
    const float* win_seq = (const float*)d_in[0];
    const float* win_pcc = (const float*)d_in[1];
    const float* ga      = (const float*)d_in[2];
    const float* emb     = (const float*)d_in[4];
    const float* fgc_w   = (const float*)d_in[5];
    const float* fgc_b   = (const float*)d_in[6];
    const float* w_c     = (const float*)d_in[7];
    const float* ln_g    = (const float*)d_in[8];
    const float* ln_b    = (const float*)d_in[9];
    const float* A1      = (const float*)d_in[10];
    const float* WB1     = (const float*)d_in[11];
    const float* WC1     = (const float*)d_in[12];
    const float* Wdt1    = (const float*)d_in[13];
    const float* D1      = (const float*)d_in[14];
    const float* Wout1   = (const float*)d_in[15];
    const float* A2      = (const float*)d_in[16];
    const float* WB2     = (const float*)d_in[17];
    const float* WC2     = (const float*)d_in[18];
    const float* Wdt2    = (const float*)d_in[19];
    const float* D2      = (const float*)d_in[20];
    const float* Wout2   = (const float*)d_in[21];
    const float* W_gate  = (const float*)d_in[22];
    const float* b_gate  = (const float*)d_in[23];
    const float* rln_g   = (const float*)d_in[24];
    const float* rln_b   = (const float*)d_in[25];
    const float* Wr      = (const float*)d_in[26];
    const float* brr     = (const float*)d_in[27];
    const float* We      = (const float*)d_in[28];
    const float* W1      = (const float*)d_in[29];
    const float* b1      = (const float*)d_in[30];
    const float* W2      = (const float*)d_in[31];
    const float* b2      = (const float*)d_in[32];
    const float* W3      = (const float*)d_in[33];
    const float* b3      = (const float*)d_in[34];
    const float* W4      = (const float*)d_in[35];
    const float* b4      = (const float*)d_in[36];
    float* out = (float*)d_out;
    float* ws  = (float*)d_ws;

    size_t off = 0;
    auto alloc = [&](size_t n){ size_t o = off; off += (n + 63) & ~(size_t)63; return o; };
    size_t o_tabc = alloc(SEQL), o_tabs = alloc(SEQL);
    size_t o_Ct = alloc((size_t)SEQL*FRQ), o_St = alloc((size_t)SEQL*FRQ);
    size_t o_Cf = alloc((size_t)SEQL*FRQ), o_Sf = alloc((size_t)SEQL*FRQ);
    size_t o_wcs = alloc(NWW*EMB);
    size_t o_ewr = alloc(NWW*EMB), o_ewi = alloc(NWW*EMB);
    size_t o_wre = alloc((size_t)NBW*FRQ), o_wim = alloc((size_t)NBW*FRQ);
    size_t o_wpk = alloc((size_t)2228224);    // 4,456,448 fp16 = 17*4*4*16384
    size_t o_zre = alloc((size_t)NBW*FRQ), o_zim = alloc((size_t)NBW*FRQ);
    size_t o_ff  = alloc((size_t)NBW*SEQL);
    size_t o_x1  = alloc((size_t)BSZ*NRR*NRR);
    size_t o_dt1 = alloc((size_t)BSZ*NRR*NRR);
    size_t o_BT1 = alloc((size_t)BSZ*NRR*DST), o_CT1 = alloc((size_t)BSZ*NRR*DST);
    size_t o_pool= alloc((size_t)BSZ*NRR);
    size_t o_o1  = alloc((size_t)NBW*SEQL);
    size_t o_tf  = alloc((size_t)NBW*SEQL);
    size_t o_x2  = alloc((size_t)NBW*SEQL);
    size_t o_dt2 = alloc((size_t)NBW*SEQL);
    size_t o_BT2 = alloc((size_t)NBW*DST), o_CT2 = alloc((size_t)NBW*DST);
    size_t o_y2  = alloc((size_t)NBW*SEQL);
    size_t o_o2  = alloc((size_t)NBW*SEQL);
    size_t o_fr2 = alloc((size_t)NBW*SEQL);
    size_t o_fus = alloc((size_t)BSZ*NRR*EDD);
    size_t o_gte = alloc((size_t)BSZ*NRR*4);
    size_t o_sup = alloc((size_t)BSZ*4*NRR*EDD);
    size_t o_eo  = alloc((size_t)BSZ*4*NRR*EDD);
    size_t o_moe = alloc((size_t)BSZ*NRR*EDD);
    size_t o_p1  = alloc((size_t)KSPLIT*BSZ*512);
    size_t o_h1  = alloc((size_t)BSZ*512);
    size_t o_h2  = alloc((size_t)BSZ*256);
    size_t o_h3  = alloc((size_t)BSZ*128);
    if (ws_size < off*sizeof(float)) return; // workspace too small -> visible failure

    #define WSP(o) (ws + (o))
    int nMk = (SEQL*FRQ + 255)/256;
    k_tables<<<(SEQL+255)/256, 256, 0, stream>>>(WSP(o_tabc), WSP(o_tabs));
    k_mk_tmaj<<<nMk, 256, 0, stream>>>(WSP(o_tabc), WSP(o_tabs), WSP(o_Ct), WSP(o_St));
    k_mk_fmaj<<<nMk, 256, 0, stream>>>(WSP(o_tabc), WSP(o_tabs), WSP(o_Cf), WSP(o_Sf));
    k_wcsm<<<NWW, EMB, 0, stream>>>(w_c, WSP(o_wcs));
    k_ew<<<(NWW*EMB+255)/256, 256, 0, stream>>>(emb, fgc_w, WSP(o_ewr), WSP(o_ewi));
    k_wprep<<<136, 256, 0, stream>>>(fgc_w, (_Float16*)WSP(o_wpk));
    k_dft<<<dim3(3, 68), 256, 0, stream>>>(win_seq, WSP(o_Ct), WSP(o_St), WSP(o_wre), WSP(o_wim));
    k_fgc_fused<<<dim3(19, NBW), 256, 0, stream>>>(WSP(o_wre), WSP(o_wim), WSP(o_ewr), WSP(o_ewi),
                                                   fgc_b, WSP(o_wcs),
                                                   (const _Float16*)WSP(o_wpk),
                                                   WSP(o_zre), WSP(o_zim));
    k_irfft<<<dim3(5, 68), 256, 0, stream>>>(WSP(o_zre), WSP(o_zim), WSP(o_Cf), WSP(o_Sf), WSP(o_ff));
    // branch 1: pcc -> sscan1 -> out1 -> LN
    k_x1mean<<<(BSZ*NRR*NRR+255)/256, 256, 0, stream>>>(win_pcc, WSP(o_x1));
    k_dt1<<<(BSZ*NRR*NRR+255)/256, 256, 0, stream>>>(WSP(o_x1), Wdt1, WSP(o_dt1));
    k_btct1<<<(BSZ*NRR*DST+255)/256, 256, 0, stream>>>(WSP(o_x1), WB1, WC1, WSP(o_BT1), WSP(o_CT1));
    k_sscan1<<<(BSZ*NRR+255)/256, 256, 0, stream>>>(WSP(o_x1), WSP(o_dt1), WSP(o_BT1), WSP(o_CT1),
                                                    A1, D1, WSP(o_pool));
    k_out1<<<(NBW*SEQL+255)/256, 256, 0, stream>>>(WSP(o_pool), Wout1, WSP(o_o1));
    k_ln<<<NBW, 256, 0, stream>>>(WSP(o_o1), ln_g, ln_b, WSP(o_tf));
    // branch 2: freq_feat -> adj -> sscan2 -> out2 -> LN
    k_x2<<<(NBW*SEQL+255)/256, 256, 0, stream>>>(ga, WSP(o_ff), WSP(o_x2));
    k_dt2<<<dim3(5, 68), 256, 0, stream>>>(WSP(o_x2), Wdt2, WSP(o_dt2));
    k_btct2<<<(NBW*DST+255)/256, 256, 0, stream>>>(WSP(o_x2), WB2, WC2, WSP(o_BT2), WSP(o_CT2));
    k_sscan2<<<(BSZ*SEQL+255)/256, 256, 0, stream>>>(WSP(o_x2), WSP(o_dt2), WSP(o_BT2), WSP(o_CT2),
                                                     A2, D2, WSP(o_y2));
    k_out2<<<dim3(5, 68), 256, 0, stream>>>(WSP(o_y2), Wout2, WSP(o_o2));
    k_ln<<<NBW, 256, 0, stream>>>(WSP(o_o2), ln_g, ln_b, WSP(o_fr2));
    // fusion + MoE + MLP
    k_gatefusion<<<(BSZ*NRR*EDD+255)/256, 256, 0, stream>>>(WSP(o_fr2), WSP(o_tf), W_gate, b_gate, WSP(o_fus));
    k_gates<<<BSZ*NRR, 64, 0, stream>>>(WSP(o_fus), rln_g, rln_b, Wr, brr, WSP(o_gte));
    k_support<<<(BSZ*4*NRR*EDD+255)/256, 256, 0, stream>>>(WSP(o_fus), We, WSP(o_sup));
    k_eout<<<(BSZ*4*NRR*EDD+255)/256, 256, 0, stream>>>(ga, WSP(o_sup), WSP(o_eo));
    k_moe<<<(BSZ*NRR*EDD+255)/256, 256, 0, stream>>>(WSP(o_eo), WSP(o_gte), WSP(o_moe));
    k_mlp1p<<<dim3(KSPLIT, 2), 256, 0, stream>>>(WSP(o_moe), W1, WSP(o_p1));
    k_mlp1c<<<(BSZ*512)/256, 256, 0, stream>>>(WSP(o_p1), b1, WSP(o_h1));
    k_mlp2<<<(BSZ*256)/256, 256, 0, stream>>>(WSP(o_h1), W2, b2, WSP(o_h2));
    k_mlp3<<<(BSZ*128+255)/256, 256, 0, stream>>>(WSP(o_h2), W3, b3, WSP(o_h3));
    k_mlp4<<<1, 64, 0, stream>>>(WSP(o_h3), W4, b4, out);
    #undef WSP
}